// Round 5
// baseline (8024.422 us; speedup 1.0000x reference)
//
#include <hip/hip_runtime.h>
#include <hip/hip_bf16.h>

typedef unsigned short ushort_t;
typedef short bf16x8 __attribute__((ext_vector_type(8)));
typedef float f32x4  __attribute__((ext_vector_type(4)));

#define BATCH   2
#define FRAMES  8
#define GRID_   14
#define NTOK    196
#define PS      16
#define IMG     224
#define L_SEQ   1568
#define DM      384
#define DI      768
#define DTR     24
#define DS      16
#define DEPTH   24
#define KCONV   4
#define NROWS   (BATCH*L_SEQ)   // 3136
#define EPS_    1e-5f
#define NCHUNK  32
#define CLEN    49              // 32*49 = 1568

__device__ __forceinline__ ushort_t f2us(float f){
    __hip_bfloat16 h = __float2bfloat16(f);
    return *reinterpret_cast<ushort_t*>(&h);
}
__device__ __forceinline__ float us2f(ushort_t u){
    return __uint_as_float(((unsigned int)u) << 16);
}

// ---------------- patchify: x (B,3,T,224,224) f32 -> patches (3136,768) bf16 -----
__global__ __launch_bounds__(256) void patchify_kernel(const float* __restrict__ x,
                                                       ushort_t* __restrict__ patches){
    int idx = blockIdx.x*256 + threadIdx.x;
    if (idx >= NROWS*768) return;
    int k   = idx % 768;
    int r   = idx / 768;
    int tok = r % NTOK;
    int bt  = r / NTOK;
    int t = bt % FRAMES, b = bt / FRAMES;
    int gy = tok / GRID_, gx = tok % GRID_;
    int c = k / 256; int rem = k % 256; int py = rem/16, px = rem%16;
    long xo = (((long)(b*3 + c)*FRAMES + t)*IMG + (gy*PS+py))*IMG + (gx*PS+px);
    patches[idx] = f2us(x[xo]);
}

// ---------------- generic f32 -> bf16 convert ------------------------------------
__global__ __launch_bounds__(256) void convert_kernel(const float* __restrict__ in,
                                                      ushort_t* __restrict__ out, int n){
    int i = blockIdx.x*256 + threadIdx.x;
    if (i < n) out[i] = f2us(in[i]);
}

// ---------------- per-layer weight conversion (wi|wo|wxf|wxb|wdtf|wdtb) ----------
#define WI_SZ  (2*DI*DM)      // 589824
#define WO_SZ  (DM*DI)        // 294912
#define WX_SZ  (56*DI)        // 43008
#define WDT_SZ (DI*32)        // 24576 (padded K 24->32)
#define WCVT_TOTAL (WI_SZ + WO_SZ + 2*WX_SZ + 2*WDT_SZ)   // 1,019,904

__global__ __launch_bounds__(256) void convert_layer_kernel(
        const float* __restrict__ wi, const float* __restrict__ wo,
        const float* __restrict__ wxf, const float* __restrict__ wxb,
        const float* __restrict__ wdtf, const float* __restrict__ wdtb,
        ushort_t* __restrict__ out)
{
    int gid = blockIdx.x*256 + threadIdx.x;
    if (gid >= WCVT_TOTAL) return;
    float v;
    if (gid < WI_SZ)                       v = wi[gid];
    else if (gid < WI_SZ+WO_SZ)            v = wo[gid - WI_SZ];
    else if (gid < WI_SZ+WO_SZ+WX_SZ)      v = wxf[gid - WI_SZ - WO_SZ];
    else if (gid < WI_SZ+WO_SZ+2*WX_SZ)    v = wxb[gid - WI_SZ - WO_SZ - WX_SZ];
    else if (gid < WI_SZ+WO_SZ+2*WX_SZ+WDT_SZ){
        int i = gid - (WI_SZ+WO_SZ+2*WX_SZ);
        int rr = i >> 5, c = i & 31;
        v = (c < DTR) ? wdtf[rr*DTR + c] : 0.f;
    } else {
        int i = gid - (WI_SZ+WO_SZ+2*WX_SZ+WDT_SZ);
        int rr = i >> 5, c = i & 31;
        v = (c < DTR) ? wdtb[rr*DTR + c] : 0.f;
    }
    out[gid] = f2us(v);
}

// ---------------- MFMA GEMM, bf16 A: C[M,N] = A[M,K] * W[N,K]^T -------------------
// modes: 1 in_proj split -> bf16 xi/zi; 2 patch epilogue -> f32 + aux
__global__ __launch_bounds__(256) void gemm_bf16A_kernel(
        const ushort_t* __restrict__ A, int lda,
        const ushort_t* __restrict__ W, int ldw,
        int K, int N,
        float* __restrict__ out0,
        ushort_t* __restrict__ outb0, ushort_t* __restrict__ outb1,
        int mode,
        const float* __restrict__ aux0, const float* __restrict__ aux1,
        const float* __restrict__ aux2)
{
    int tid  = threadIdx.x;
    int wave = tid >> 6, lane = tid & 63;
    int l15 = lane & 15, quad = lane >> 4;
    int m0 = blockIdx.y * 64, n0 = blockIdx.x * 64;

    const ushort_t* wp  = W + (long)(n0 + wave*16 + l15)*ldw + quad*8;
    const ushort_t* ap0 = A + (long)(m0 + l15)*lda + quad*8;

    f32x4 acc[4] = {f32x4{0,0,0,0}, f32x4{0,0,0,0}, f32x4{0,0,0,0}, f32x4{0,0,0,0}};

    for (int k0 = 0; k0 < K; k0 += 32){
        bf16x8 bfrag = *reinterpret_cast<const bf16x8*>(wp + k0);
        #pragma unroll
        for (int mt = 0; mt < 4; mt++){
            bf16x8 afrag = *reinterpret_cast<const bf16x8*>(ap0 + (long)mt*16*lda + k0);
            acc[mt] = __builtin_amdgcn_mfma_f32_16x16x32_bf16(afrag, bfrag, acc[mt], 0, 0, 0);
        }
    }

    int cn = n0 + wave*16 + l15;
    #pragma unroll
    for (int mt = 0; mt < 4; mt++){
        #pragma unroll
        for (int r = 0; r < 4; r++){
            int row = m0 + mt*16 + quad*4 + r;
            float v = acc[mt][r];
            if (mode == 1){
                if (cn < DI) outb0[(long)row*DI + cn] = f2us(v);
                else         outb1[(long)row*DI + cn - DI] = f2us(v);
            } else { // mode 2: patch embed epilogue
                int tok = row % NTOK, t = (row/NTOK) % FRAMES;
                out0[(long)row*N + cn] = v + aux0[cn] + aux1[tok*DM+cn] + aux2[t*DM+cn];
            }
        }
    }
}

// ---------------- MFMA GEMM, f32 A (in-kernel bf16 convert) -----------------------
// modes: 0 plain f32 (A2 optional add); 3 dt softplus + bias(z); 4 xproj cn<56
__device__ __forceinline__ bf16x8 frag_from_f32(const float* p, const float* p2){
    float4 lo = *(const float4*)p;
    float4 hi = *(const float4*)(p+4);
    if (p2){
        float4 lo2 = *(const float4*)p2;
        float4 hi2 = *(const float4*)(p2+4);
        lo.x+=lo2.x; lo.y+=lo2.y; lo.z+=lo2.z; lo.w+=lo2.w;
        hi.x+=hi2.x; hi.y+=hi2.y; hi.z+=hi2.z; hi.w+=hi2.w;
    }
    bf16x8 r;
    r[0]=(short)f2us(lo.x); r[1]=(short)f2us(lo.y); r[2]=(short)f2us(lo.z); r[3]=(short)f2us(lo.w);
    r[4]=(short)f2us(hi.x); r[5]=(short)f2us(hi.y); r[6]=(short)f2us(hi.z); r[7]=(short)f2us(hi.w);
    return r;
}

__global__ __launch_bounds__(256) void gemm_f32A_kernel(
        const float* __restrict__ A, int lda, long strideA, int KrealA,
        const float* __restrict__ A2,
        const ushort_t* __restrict__ W, int ldw, long strideW,
        int K, int N,
        float* __restrict__ out0, long strideO0,
        int mode,
        const float* __restrict__ aux0, const float* __restrict__ aux1)
{
    int z = blockIdx.z;
    A    += (long)z * strideA;
    W    += (long)z * strideW;
    out0 += (long)z * strideO0;

    int tid  = threadIdx.x;
    int wave = tid >> 6, lane = tid & 63;
    int l15 = lane & 15, quad = lane >> 4;
    int m0 = blockIdx.y * 64, n0 = blockIdx.x * 64;

    const ushort_t* wp  = W + (long)(n0 + wave*16 + l15)*ldw + quad*8;
    const float*    ap0 = A + (long)(m0 + l15)*lda + quad*8;
    const float*    ap2 = A2 ? A2 + (long)(m0 + l15)*lda + quad*8 : nullptr;

    f32x4 acc[4] = {f32x4{0,0,0,0}, f32x4{0,0,0,0}, f32x4{0,0,0,0}, f32x4{0,0,0,0}};

    for (int k0 = 0; k0 < K; k0 += 32){
        bf16x8 bfrag = *reinterpret_cast<const bf16x8*>(wp + k0);
        #pragma unroll
        for (int mt = 0; mt < 4; mt++){
            bf16x8 afrag = frag_from_f32(ap0 + (long)mt*16*lda + k0,
                                         ap2 ? ap2 + (long)mt*16*lda + k0 : nullptr);
            if (KrealA){
                int kb = k0 + quad*8;
                #pragma unroll
                for (int j = 0; j < 8; j++) if (kb + j >= KrealA) afrag[j] = 0;
            }
            acc[mt] = __builtin_amdgcn_mfma_f32_16x16x32_bf16(afrag, bfrag, acc[mt], 0, 0, 0);
        }
    }

    int cn = n0 + wave*16 + l15;
    #pragma unroll
    for (int mt = 0; mt < 4; mt++){
        #pragma unroll
        for (int r = 0; r < 4; r++){
            int row = m0 + mt*16 + quad*4 + r;
            float v = acc[mt][r];
            if (mode == 0){
                out0[(long)row*N + cn] = v;
            } else if (mode == 3){
                const float* bias = z ? aux1 : aux0;
                float xs = v + bias[cn];
                out0[(long)row*N + cn] = (xs > 20.f) ? xs : log1pf(__expf(xs));
            } else { // mode 4: xproj
                if (cn < 56) out0[(long)row*56 + cn] = v;
            }
        }
    }
}

// ---------------- rmsnorm (+ residual add), bf16 out -----------------------------
__global__ __launch_bounds__(128) void rmsnorm_kernel(
        float* __restrict__ res, const float* __restrict__ h,
        ushort_t* __restrict__ outb, const float* __restrict__ w)
{
    int r = blockIdx.x; int tid = threadIdx.x;
    const float* hr = h + (long)r*DM;
    float* rr = res + (long)r*DM;
    float v[3]; float ss = 0.f;
    #pragma unroll
    for (int i = 0; i < 3; i++){
        int c = tid + i*128;
        float x = rr[c] + hr[c];
        rr[c] = x; v[i] = x; ss += x*x;
    }
    #pragma unroll
    for (int off = 32; off; off >>= 1) ss += __shfl_down(ss, off, 64);
    __shared__ float wsum[2];
    if ((tid & 63) == 0) wsum[tid >> 6] = ss;
    __syncthreads();
    float scale = rsqrtf((wsum[0] + wsum[1]) / (float)DM + EPS_);
    #pragma unroll
    for (int i = 0; i < 3; i++){
        int c = tid + i*128;
        outb[(long)r*DM + c] = f2us(v[i] * scale * w[c]);
    }
}

// ---------------- depthwise causal conv + silu, x4 vectorized --------------------
// xi bf16 (b,l,d); out xc2 f32 (dir,b,p,d)
__global__ __launch_bounds__(256) void conv_kernel(
        const ushort_t* __restrict__ xi,
        const float* __restrict__ cw_f, const float* __restrict__ cb_f,
        const float* __restrict__ cw_b, const float* __restrict__ cb_b,
        float* __restrict__ xc)
{
    int vidx = blockIdx.x*256 + threadIdx.x;
    if (vidx >= 2*NROWS*192) return;
    int dq = vidx % 192; int d4 = dq*4;
    int r2 = vidx / 192;
    int dir = r2 / NROWS;
    int rr  = r2 % NROWS;
    int b = rr / L_SEQ, p = rr % L_SEQ;
    const float* cw = dir ? cw_b : cw_f;
    const float* cb = dir ? cb_b : cb_f;
    float w[4][4];
    #pragma unroll
    for (int dd = 0; dd < 4; dd++){
        float4 wv = *(const float4*)(cw + (d4+dd)*KCONV);
        w[dd][0]=wv.x; w[dd][1]=wv.y; w[dd][2]=wv.z; w[dd][3]=wv.w;
    }
    float4 acc = *(const float4*)(cb + d4);
    #pragma unroll
    for (int j = 0; j < KCONV; j++){
        int pp = p - (KCONV-1) + j;
        if (pp >= 0){
            int phys = dir ? (L_SEQ-1-pp) : pp;
            ushort4 u = *(const ushort4*)(xi + ((long)b*L_SEQ + phys)*DI + d4);
            acc.x += w[0][j]*us2f(u.x);
            acc.y += w[1][j]*us2f(u.y);
            acc.z += w[2][j]*us2f(u.z);
            acc.w += w[3][j]*us2f(u.w);
        }
    }
    float4 o;
    o.x = acc.x/(1.f+__expf(-acc.x));
    o.y = acc.y/(1.f+__expf(-acc.y));
    o.z = acc.z/(1.f+__expf(-acc.z));
    o.w = acc.w/(1.f+__expf(-acc.w));
    *(float4*)(xc + (long)r2*DI + d4) = o;
}

// ---------------- chunked selective scan -----------------------------------------
__global__ __launch_bounds__(256) void scan_pass1_kernel(
        const float* __restrict__ xc2, const float* __restrict__ dt2,
        const float* __restrict__ xdbl2,
        const float* __restrict__ Alog_f, const float* __restrict__ Alog_b,
        float* __restrict__ Pbuf, float* __restrict__ Sbuf)
{
    int dchunk = blockIdx.x;
    int chunk  = blockIdx.y;
    int z      = blockIdx.z;
    int b = z & 1, dir = z >> 1;
    int tid = threadIdx.x;
    int n = tid & 15, dg = tid >> 4;
    int dbase = dchunk*16;
    int d = dbase + dg;

    const float* xc = xc2 + (long)dir*NROWS*DI;
    const float* dt = dt2 + (long)dir*NROWS*DI;
    const float* xd = xdbl2 + (long)dir*NROWS*56;
    const float* Alog = dir ? Alog_b : Alog_f;
    float Aval = -__expf(Alog[d*DS + n]);

    __shared__ float sdt[CLEN][16], sxc[CLEN][16], sB[CLEN][16];
    int c0 = chunk * CLEN;
    for (int e = tid; e < CLEN*4; e += 256){
        int s = e >> 2, q4 = (e & 3)*4;
        long row = (long)b*L_SEQ + c0 + s;
        *(float4*)&sdt[s][q4] = *(const float4*)(dt + row*DI + dbase + q4);
        *(float4*)&sxc[s][q4] = *(const float4*)(xc + row*DI + dbase + q4);
        *(float4*)&sB[s][q4]  = *(const float4*)(xd + row*56 + DTR + q4);
    }
    __syncthreads();

    float h = 0.f, dts = 0.f;
    for (int s = 0; s < CLEN; s++){
        float dtv = sdt[s][dg], xcv = sxc[s][dg];
        dts += dtv;
        h = __expf(dtv*Aval)*h + (dtv*xcv)*sB[s][n];
    }
    long idx = (((long)z*NCHUNK + chunk)*DI + d)*DS + n;
    Pbuf[idx] = __expf(Aval*dts);
    Sbuf[idx] = h;
}

// pass2 with folded combine prefix
__global__ __launch_bounds__(256) void scan_pass2_kernel(
        const float* __restrict__ xc2, const float* __restrict__ dt2,
        const float* __restrict__ xdbl2, const ushort_t* __restrict__ zi,
        const float* __restrict__ Alog_f, const float* __restrict__ Dp_f,
        const float* __restrict__ Alog_b, const float* __restrict__ Dp_b,
        const float* __restrict__ Pbuf, const float* __restrict__ Sbuf,
        float* __restrict__ ys_f, float* __restrict__ ys_b)
{
    int dchunk = blockIdx.x;
    int chunk  = blockIdx.y;
    int z      = blockIdx.z;
    int b = z & 1, dir = z >> 1;
    int tid = threadIdx.x;
    int n = tid & 15, dg = tid >> 4;
    int dbase = dchunk*16;
    int d = dbase + dg;

    const float* xc = xc2 + (long)dir*NROWS*DI;
    const float* dt = dt2 + (long)dir*NROWS*DI;
    const float* xd = xdbl2 + (long)dir*NROWS*56;
    const float* Alog = dir ? Alog_b : Alog_f;
    const float* Dpp  = dir ? Dp_b   : Dp_f;
    float* ys = dir ? ys_b : ys_f;

    float Aval = -__expf(Alog[d*DS + n]);
    float Dval = Dpp[d];

    __shared__ float sdt[CLEN][16], sxc[CLEN][16], sB[CLEN][16], sC[CLEN][16], sz[CLEN][16];
    int c0 = chunk * CLEN;
    for (int e = tid; e < CLEN*4; e += 256){
        int s = e >> 2, q4 = (e & 3)*4;
        int p = c0 + s;
        int phys = dir ? (L_SEQ-1-p) : p;
        long row  = (long)b*L_SEQ + p;
        long prow = (long)b*L_SEQ + phys;
        *(float4*)&sdt[s][q4] = *(const float4*)(dt + row*DI + dbase + q4);
        *(float4*)&sxc[s][q4] = *(const float4*)(xc + row*DI + dbase + q4);
        *(float4*)&sB[s][q4]  = *(const float4*)(xd + row*56 + DTR + q4);
        *(float4*)&sC[s][q4]  = *(const float4*)(xd + row*56 + DTR + DS + q4);
        ushort4 u = *(const ushort4*)(zi + prow*DI + dbase + q4);
        float4 zf; zf.x=us2f(u.x); zf.y=us2f(u.y); zf.z=us2f(u.z); zf.w=us2f(u.w);
        *(float4*)&sz[s][q4] = zf;
    }

    // combine prefix: Hin = scan of (P,S) over chunks < chunk (overlaps staging)
    float h = 0.f;
    {
        long cidx = ((long)z*NCHUNK*DI + d)*DS + n;
        for (int c = 0; c < chunk; c++){
            h = Pbuf[cidx]*h + Sbuf[cidx];
            cidx += (long)DI*DS;
        }
    }
    __syncthreads();

    for (int s = 0; s < CLEN; s++){
        float dtv = sdt[s][dg], xcv = sxc[s][dg];
        float dA = __expf(dtv*Aval);
        h = dA*h + (dtv*xcv)*sB[s][n];
        float contrib = h * sC[s][n];
        contrib += __shfl_xor(contrib, 8, 16);
        contrib += __shfl_xor(contrib, 4, 16);
        contrib += __shfl_xor(contrib, 2, 16);
        contrib += __shfl_xor(contrib, 1, 16);
        if (n == 0){
            int p = c0 + s;
            int phys = dir ? (L_SEQ-1-p) : p;
            long orow = (long)b*L_SEQ + phys;
            float zv = sz[s][dg];
            float sg = 1.f/(1.f + __expf(-zv));
            ys[orow*DI + d] = (contrib + Dval*xcv) * (zv*sg);
        }
    }
}

// ---------------- final rmsnorm --------------------------------------------------
__global__ __launch_bounds__(128) void rmsnorm_final_kernel(
        const float* __restrict__ res, const float* __restrict__ h,
        const float* __restrict__ w, float* __restrict__ out)
{
    int r = blockIdx.x; int tid = threadIdx.x;
    const float* hr = h + (long)r*DM;
    const float* rr = res + (long)r*DM;
    float v[3]; float ss = 0.f;
    #pragma unroll
    for (int i = 0; i < 3; i++){
        int c = tid + i*128;
        float x = rr[c] + hr[c];
        v[i] = x; ss += x*x;
    }
    #pragma unroll
    for (int off = 32; off; off >>= 1) ss += __shfl_down(ss, off, 64);
    __shared__ float wsum[2];
    if ((tid & 63) == 0) wsum[tid >> 6] = ss;
    __syncthreads();
    float scale = rsqrtf((wsum[0] + wsum[1]) / (float)DM + EPS_);
    #pragma unroll
    for (int i = 0; i < 3; i++){
        int c = tid + i*128;
        out[(long)r*DM + c] = v[i] * scale * w[c];
    }
}

extern "C" void kernel_launch(void* const* d_in, const int* in_sizes, int n_in,
                              void* d_out, int out_size, void* d_ws, size_t ws_size,
                              hipStream_t stream)
{
    const float* x         = (const float*)d_in[0];
    const float* patch_w   = (const float*)d_in[1];
    const float* patch_b   = (const float*)d_in[2];
    const float* pos_embed = (const float*)d_in[3];
    const float* temp_pos  = (const float*)d_in[4];
    const float* in_proj   = (const float*)d_in[5];
    const float* conv_w    = (const float*)d_in[6];
    const float* conv_b    = (const float*)d_in[7];
    const float* xproj_w   = (const float*)d_in[8];
    const float* dt_w      = (const float*)d_in[9];
    const float* dt_b      = (const float*)d_in[10];
    const float* A_log     = (const float*)d_in[11];
    const float* Dp        = (const float*)d_in[12];
    const float* conv_w_b  = (const float*)d_in[13];
    const float* conv_b_b  = (const float*)d_in[14];
    const float* xproj_w_b = (const float*)d_in[15];
    const float* dt_w_b    = (const float*)d_in[16];
    const float* dt_b_b    = (const float*)d_in[17];
    const float* A_log_b   = (const float*)d_in[18];
    const float* Dp_b      = (const float*)d_in[19];
    const float* out_proj  = (const float*)d_in[20];
    const float* norm_w    = (const float*)d_in[21];
    const float* norm_f    = (const float*)d_in[22];

    float* ws = (float*)d_ws;
    size_t off = 0;
    float* hidden   = ws + off; off += (size_t)NROWS*DM;           // 1,204,224
    float* residual = ws + off; off += (size_t)NROWS*DM;
    float* hnormreg = ws + off; off += (size_t)NROWS*DM/2;         // bf16 hnorm; Pbuf head
    float* xireg    = ws + off; off += (size_t)NROWS*DI/2;         // bf16 xi; Pbuf tail
    float* zireg    = ws + off; off += (size_t)NROWS*DI/2;         // bf16 zi
    float* xc2      = ws + off; off += (size_t)2*NROWS*DI;         // f32; patches_bf alias
    float* xdbl2    = ws + off; off += (size_t)2*NROWS*56;
    float* dt2      = ws + off; off += (size_t)2*NROWS*DI;
    float* ysf      = ws + off; off += (size_t)NROWS*DI;
    float* ysb      = ws + off; off += (size_t)NROWS*DI;
    float* Sbuf     = ws + off; off += (size_t)4*NCHUNK*DI*DS;     // 1,572,864
    float* wbf_f    = ws + off; off += (size_t)(WCVT_TOTAL+1)/2;
    float* wpbf_f   = ws + off; off += (size_t)(DM*DI+1)/2;

    ushort_t* hnorm_bf   = (ushort_t*)hnormreg;
    ushort_t* xi_bf      = (ushort_t*)xireg;
    ushort_t* zi_bf      = (ushort_t*)zireg;
    ushort_t* patches_bf = (ushort_t*)xc2;     // dead once conv writes xc2 (layer 0)
    ushort_t* wbf        = (ushort_t*)wbf_f;
    ushort_t* wp_bf      = (ushort_t*)wpbf_f;
    ushort_t* wi_bf  = wbf;
    ushort_t* wo_bf  = wbf + WI_SZ;
    ushort_t* wx_bf  = wbf + WI_SZ + WO_SZ;           // [2][WX_SZ]
    ushort_t* wdt_bf = wbf + WI_SZ + WO_SZ + 2*WX_SZ; // [2][WDT_SZ]
    float* Pbuf = hnormreg;   // 1,572,864 floats: spans hnorm (602,112) + xi head; both dead by pass1

    hipMemsetAsync(residual, 0, (size_t)NROWS*DM*sizeof(float), stream);

    patchify_kernel<<<(NROWS*768+255)/256, 256, 0, stream>>>(x, patches_bf);
    convert_kernel<<<(DM*DI+255)/256, 256, 0, stream>>>(patch_w, wp_bf, DM*DI);
    gemm_bf16A_kernel<<<dim3(DM/64, NROWS/64), 256, 0, stream>>>(
        patches_bf, DI, wp_bf, DI, DI, DM,
        hidden, nullptr, nullptr, 2, patch_b, pos_embed, temp_pos);

    for (int l = 0; l < DEPTH; l++){
        convert_layer_kernel<<<(WCVT_TOTAL+255)/256, 256, 0, stream>>>(
            in_proj + (size_t)l*WI_SZ, out_proj + (size_t)l*WO_SZ,
            xproj_w + (size_t)l*WX_SZ, xproj_w_b + (size_t)l*WX_SZ,
            dt_w + (size_t)l*DI*DTR, dt_w_b + (size_t)l*DI*DTR, wbf);

        rmsnorm_kernel<<<NROWS, 128, 0, stream>>>(residual, hidden, hnorm_bf,
                                                  norm_w + (size_t)l*DM);
        // in_proj -> xi_bf, zi_bf
        gemm_bf16A_kernel<<<dim3(2*DI/64, NROWS/64), 256, 0, stream>>>(
            hnorm_bf, DM, wi_bf, DM, DM, 2*DI,
            nullptr, xi_bf, zi_bf, 1, nullptr, nullptr, nullptr);

        conv_kernel<<<(2*NROWS*192+255)/256, 256, 0, stream>>>(
            xi_bf, conv_w + (size_t)l*DI*KCONV, conv_b + (size_t)l*DI,
            conv_w_b + (size_t)l*DI*KCONV, conv_b_b + (size_t)l*DI, xc2);

        // xproj fwd+bwd: xc2(f32) x wx^T -> xdbl2 f32
        gemm_f32A_kernel<<<dim3(1, NROWS/64, 2), 256, 0, stream>>>(
            xc2, DI, (long)NROWS*DI, 0, nullptr,
            wx_bf, DI, WX_SZ, DI, 64,
            xdbl2, (long)NROWS*56, 4, nullptr, nullptr);

        // dt fwd+bwd: xdbl2(f32, lda=56, Kreal=24) x wdt(768,32)^T + bias, softplus
        gemm_f32A_kernel<<<dim3(DI/64, NROWS/64, 2), 256, 0, stream>>>(
            xdbl2, 56, (long)NROWS*56, DTR, nullptr,
            wdt_bf, 32, WDT_SZ, 32, DI,
            dt2, (long)NROWS*DI, 3,
            dt_b + (size_t)l*DI, dt_b_b + (size_t)l*DI);

        scan_pass1_kernel<<<dim3(DI/16, NCHUNK, 4), 256, 0, stream>>>(
            xc2, dt2, xdbl2, A_log + (size_t)l*DI*DS, A_log_b + (size_t)l*DI*DS,
            Pbuf, Sbuf);
        scan_pass2_kernel<<<dim3(DI/16, NCHUNK, 4), 256, 0, stream>>>(
            xc2, dt2, xdbl2, zi_bf,
            A_log + (size_t)l*DI*DS, Dp + (size_t)l*DI,
            A_log_b + (size_t)l*DI*DS, Dp_b + (size_t)l*DI,
            Pbuf, Sbuf, ysf, ysb);

        // out_proj: (ysf+ysb)(f32) x wo^T -> hidden
        gemm_f32A_kernel<<<dim3(DM/64, NROWS/64, 1), 256, 0, stream>>>(
            ysf, DI, 0, 0, ysb,
            wo_bf, DI, 0, DI, DM,
            hidden, 0, 0, nullptr, nullptr);
    }

    rmsnorm_final_kernel<<<NROWS, 128, 0, stream>>>(residual, hidden,
                                                    norm_f, (float*)d_out);
}

// Round 6
// 5593.538 us; speedup vs baseline: 1.4346x; 1.4346x over previous
//
#include <hip/hip_runtime.h>
#include <hip/hip_bf16.h>

typedef unsigned short ushort_t;
typedef short bf16x8 __attribute__((ext_vector_type(8)));
typedef float f32x4  __attribute__((ext_vector_type(4)));

#define BATCH   2
#define FRAMES  8
#define GRID_   14
#define NTOK    196
#define PS      16
#define IMG     224
#define L_SEQ   1568
#define DM      384
#define DI      768
#define DTR     24
#define DS      16
#define DEPTH   24
#define KCONV   4
#define NROWS   (BATCH*L_SEQ)   // 3136
#define EPS_    1e-5f
#define NCHUNK  32
#define CLEN    49              // 32*49 = 1568
#define DTILE   64
#define NDC     (DI/DTILE)      // 12
#define LOG2E   1.4426950408889634f

__device__ __forceinline__ ushort_t f2us(float f){
    __hip_bfloat16 h = __float2bfloat16(f);
    return *reinterpret_cast<ushort_t*>(&h);
}
__device__ __forceinline__ float us2f(ushort_t u){
    return __uint_as_float(((unsigned int)u) << 16);
}

// ---------------- patchify ------------------------------------------------------
__global__ __launch_bounds__(256) void patchify_kernel(const float* __restrict__ x,
                                                       ushort_t* __restrict__ patches){
    int idx = blockIdx.x*256 + threadIdx.x;
    if (idx >= NROWS*768) return;
    int k   = idx % 768;
    int r   = idx / 768;
    int tok = r % NTOK;
    int bt  = r / NTOK;
    int t = bt % FRAMES, b = bt / FRAMES;
    int gy = tok / GRID_, gx = tok % GRID_;
    int c = k / 256; int rem = k % 256; int py = rem/16, px = rem%16;
    long xo = (((long)(b*3 + c)*FRAMES + t)*IMG + (gy*PS+py))*IMG + (gx*PS+px);
    patches[idx] = f2us(x[xo]);
}

__global__ __launch_bounds__(256) void convert_kernel(const float* __restrict__ in,
                                                      ushort_t* __restrict__ out, int n){
    int i = blockIdx.x*256 + threadIdx.x;
    if (i < n) out[i] = f2us(in[i]);
}

// ---------------- per-layer weight conversion ------------------------------------
#define WI_SZ  (2*DI*DM)
#define WO_SZ  (DM*DI)
#define WX_SZ  (56*DI)
#define WDT_SZ (DI*32)
#define WCVT_TOTAL (WI_SZ + WO_SZ + 2*WX_SZ + 2*WDT_SZ)

__global__ __launch_bounds__(256) void convert_layer_kernel(
        const float* __restrict__ wi, const float* __restrict__ wo,
        const float* __restrict__ wxf, const float* __restrict__ wxb,
        const float* __restrict__ wdtf, const float* __restrict__ wdtb,
        ushort_t* __restrict__ out)
{
    int gid = blockIdx.x*256 + threadIdx.x;
    if (gid >= WCVT_TOTAL) return;
    float v;
    if (gid < WI_SZ)                       v = wi[gid];
    else if (gid < WI_SZ+WO_SZ)            v = wo[gid - WI_SZ];
    else if (gid < WI_SZ+WO_SZ+WX_SZ)      v = wxf[gid - WI_SZ - WO_SZ];
    else if (gid < WI_SZ+WO_SZ+2*WX_SZ)    v = wxb[gid - WI_SZ - WO_SZ - WX_SZ];
    else if (gid < WI_SZ+WO_SZ+2*WX_SZ+WDT_SZ){
        int i = gid - (WI_SZ+WO_SZ+2*WX_SZ);
        int rr = i >> 5, c = i & 31;
        v = (c < DTR) ? wdtf[rr*DTR + c] : 0.f;
    } else {
        int i = gid - (WI_SZ+WO_SZ+2*WX_SZ+WDT_SZ);
        int rr = i >> 5, c = i & 31;
        v = (c < DTR) ? wdtb[rr*DTR + c] : 0.f;
    }
    out[gid] = f2us(v);
}

// ---------------- MFMA GEMM, bf16 A: C[M,N] = A[M,K] * W[N,K]^T -------------------
// modes: 0 plain f32; 1 in_proj split -> bf16 xi/zi; 2 patch epilogue;
//        3 dt softplus + bias(z-sel); 4 xproj dual (f32 56 + bf16 32 pad-zero)
__global__ __launch_bounds__(256) void gemm_mfma_kernel(
        const ushort_t* __restrict__ A, int lda, long strideA,
        const ushort_t* __restrict__ W, int ldw, long strideW,
        int K, int N,
        float* __restrict__ out0, long strideO0,
        ushort_t* __restrict__ outb0, ushort_t* __restrict__ outb1, long strideOb,
        int mode,
        const float* __restrict__ aux0, const float* __restrict__ aux1,
        const float* __restrict__ aux2)
{
    int z = blockIdx.z;
    A += (long)z * strideA;
    W += (long)z * strideW;
    if (out0)  out0  += (long)z * strideO0;
    if (outb0) outb0 += (long)z * strideOb;

    int tid  = threadIdx.x;
    int wave = tid >> 6, lane = tid & 63;
    int l15 = lane & 15, quad = lane >> 4;
    int m0 = blockIdx.y * 64, n0 = blockIdx.x * 64;

    const ushort_t* wp  = W + (long)(n0 + wave*16 + l15)*ldw + quad*8;
    const ushort_t* ap0 = A + (long)(m0 + l15)*lda + quad*8;

    f32x4 acc[4] = {f32x4{0,0,0,0}, f32x4{0,0,0,0}, f32x4{0,0,0,0}, f32x4{0,0,0,0}};

    for (int k0 = 0; k0 < K; k0 += 32){
        bf16x8 bfrag = *reinterpret_cast<const bf16x8*>(wp + k0);
        #pragma unroll
        for (int mt = 0; mt < 4; mt++){
            bf16x8 afrag = *reinterpret_cast<const bf16x8*>(ap0 + (long)mt*16*lda + k0);
            acc[mt] = __builtin_amdgcn_mfma_f32_16x16x32_bf16(afrag, bfrag, acc[mt], 0, 0, 0);
        }
    }

    int cn = n0 + wave*16 + l15;
    #pragma unroll
    for (int mt = 0; mt < 4; mt++){
        #pragma unroll
        for (int r = 0; r < 4; r++){
            int row = m0 + mt*16 + quad*4 + r;
            float v = acc[mt][r];
            if (mode == 0){
                out0[(long)row*N + cn] = v;
            } else if (mode == 1){
                if (cn < DI) outb0[(long)row*DI + cn] = f2us(v);
                else         outb1[(long)row*DI + cn - DI] = f2us(v);
            } else if (mode == 2){
                int tok = row % NTOK, t = (row/NTOK) % FRAMES;
                out0[(long)row*N + cn] = v + aux0[cn] + aux1[tok*DM+cn] + aux2[t*DM+cn];
            } else if (mode == 3){
                const float* bias = z ? aux1 : aux0;
                float xs = v + bias[cn];
                out0[(long)row*N + cn] = (xs > 20.f) ? xs : log1pf(__expf(xs));
            } else { // mode 4
                if (cn < 56) out0[(long)row*56 + cn] = v;
                if (cn < 32) outb0[(long)row*32 + cn] = f2us(cn < DTR ? v : 0.f);
            }
        }
    }
}

// ---------------- rmsnorm (+ residual add), bf16 out -----------------------------
__global__ __launch_bounds__(128) void rmsnorm_kernel(
        float* __restrict__ res, const float* __restrict__ h,
        ushort_t* __restrict__ outb, const float* __restrict__ w)
{
    int r = blockIdx.x; int tid = threadIdx.x;
    const float* hr = h + (long)r*DM;
    float* rr = res + (long)r*DM;
    float v[3]; float ss = 0.f;
    #pragma unroll
    for (int i = 0; i < 3; i++){
        int c = tid + i*128;
        float x = rr[c] + hr[c];
        rr[c] = x; v[i] = x; ss += x*x;
    }
    #pragma unroll
    for (int off = 32; off; off >>= 1) ss += __shfl_down(ss, off, 64);
    __shared__ float wsum[2];
    if ((tid & 63) == 0) wsum[tid >> 6] = ss;
    __syncthreads();
    float scale = rsqrtf((wsum[0] + wsum[1]) / (float)DM + EPS_);
    #pragma unroll
    for (int i = 0; i < 3; i++){
        int c = tid + i*128;
        outb[(long)r*DM + c] = f2us(v[i] * scale * w[c]);
    }
}

// ---------------- depthwise causal conv + silu, f32 + bf16 out -------------------
__global__ __launch_bounds__(256) void conv_kernel(
        const ushort_t* __restrict__ xi,
        const float* __restrict__ cw_f, const float* __restrict__ cb_f,
        const float* __restrict__ cw_b, const float* __restrict__ cb_b,
        float* __restrict__ xc, ushort_t* __restrict__ xcb)
{
    int vidx = blockIdx.x*256 + threadIdx.x;
    if (vidx >= 2*NROWS*192) return;
    int dq = vidx % 192; int d4 = dq*4;
    int r2 = vidx / 192;
    int dir = r2 / NROWS;
    int rr  = r2 % NROWS;
    int b = rr / L_SEQ, p = rr % L_SEQ;
    const float* cw = dir ? cw_b : cw_f;
    const float* cb = dir ? cb_b : cb_f;
    float w[4][4];
    #pragma unroll
    for (int dd = 0; dd < 4; dd++){
        float4 wv = *(const float4*)(cw + (d4+dd)*KCONV);
        w[dd][0]=wv.x; w[dd][1]=wv.y; w[dd][2]=wv.z; w[dd][3]=wv.w;
    }
    float4 acc = *(const float4*)(cb + d4);
    #pragma unroll
    for (int j = 0; j < KCONV; j++){
        int pp = p - (KCONV-1) + j;
        if (pp >= 0){
            int phys = dir ? (L_SEQ-1-pp) : pp;
            ushort4 u = *(const ushort4*)(xi + ((long)b*L_SEQ + phys)*DI + d4);
            acc.x += w[0][j]*us2f(u.x);
            acc.y += w[1][j]*us2f(u.y);
            acc.z += w[2][j]*us2f(u.z);
            acc.w += w[3][j]*us2f(u.w);
        }
    }
    float4 o;
    o.x = acc.x/(1.f+__expf(-acc.x));
    o.y = acc.y/(1.f+__expf(-acc.y));
    o.z = acc.z/(1.f+__expf(-acc.z));
    o.w = acc.w/(1.f+__expf(-acc.w));
    *(float4*)(xc + (long)r2*DI + d4) = o;
    ushort4 ob; ob.x=f2us(o.x); ob.y=f2us(o.y); ob.z=f2us(o.z); ob.w=f2us(o.w);
    *(ushort4*)(xcb + (long)r2*DI + d4) = ob;
}

// ---------------- chunked selective scan: pass1 (4 n-states / thread) -------------
__global__ __launch_bounds__(256) void scan_pass1_kernel(
        const float* __restrict__ xc2, const float* __restrict__ dt2,
        const float* __restrict__ xdbl2,
        const float* __restrict__ Alog_f, const float* __restrict__ Alog_b,
        float* __restrict__ Pbuf, float* __restrict__ Sbuf)
{
    int dchunk = blockIdx.x;    // 12
    int chunk  = blockIdx.y;    // 32
    int z      = blockIdx.z;    // 4
    int b = z & 1, dir = z >> 1;
    int tid = threadIdx.x;
    int dl = tid >> 2, nq = tid & 3;
    int dbase = dchunk*DTILE;
    int d = dbase + dl;

    const float* xc = xc2 + (long)dir*NROWS*DI;
    const float* dt = dt2 + (long)dir*NROWS*DI;
    const float* xd = xdbl2 + (long)dir*NROWS*56;
    const float* Alog = dir ? Alog_b : Alog_f;

    float Av2[4];
    #pragma unroll
    for (int j = 0; j < 4; j++)
        Av2[j] = -__expf(Alog[d*DS + nq*4 + j]) * LOG2E;

    __shared__ float sdt[CLEN][DTILE], sxc[CLEN][DTILE], sB[CLEN][16];
    int c0 = chunk * CLEN;
    for (int e = tid; e < CLEN*16; e += 256){
        int s = e >> 4, q4 = (e & 15)*4;
        long row = (long)b*L_SEQ + c0 + s;
        *(float4*)&sdt[s][q4] = *(const float4*)(dt + row*DI + dbase + q4);
        *(float4*)&sxc[s][q4] = *(const float4*)(xc + row*DI + dbase + q4);
    }
    for (int e = tid; e < CLEN*4; e += 256){
        int s = e >> 2, q4 = (e & 3)*4;
        long row = (long)b*L_SEQ + c0 + s;
        *(float4*)&sB[s][q4] = *(const float4*)(xd + row*56 + DTR + q4);
    }
    __syncthreads();

    float h0=0.f,h1=0.f,h2=0.f,h3=0.f, dts=0.f;
    for (int s = 0; s < CLEN; s++){
        float dtv = sdt[s][dl], xcv = sxc[s][dl];
        float4 Bv = *(float4*)&sB[s][nq*4];
        float tmp = dtv*xcv;
        dts += dtv;
        h0 = exp2f(dtv*Av2[0])*h0 + tmp*Bv.x;
        h1 = exp2f(dtv*Av2[1])*h1 + tmp*Bv.y;
        h2 = exp2f(dtv*Av2[2])*h2 + tmp*Bv.z;
        h3 = exp2f(dtv*Av2[3])*h3 + tmp*Bv.w;
    }
    long idx = (((long)z*NCHUNK + chunk)*DI + d)*DS + nq*4;
    float4 P; P.x=exp2f(Av2[0]*dts); P.y=exp2f(Av2[1]*dts);
    P.z=exp2f(Av2[2]*dts); P.w=exp2f(Av2[3]*dts);
    float4 S; S.x=h0; S.y=h1; S.z=h2; S.w=h3;
    *(float4*)(Pbuf + idx) = P;
    *(float4*)(Sbuf + idx) = S;
}

// ---------------- combine: Sbuf -> Hin in place, float4 lanes ---------------------
__global__ __launch_bounds__(256) void scan_combine_kernel(
        const float* __restrict__ Pbuf, float* __restrict__ Sbuf)
{
    int gid = blockIdx.x*256 + threadIdx.x;     // over 4*DI*DS/4 = 12288
    if (gid >= 4*DI*DS/4) return;
    int dn4 = (gid % (DI*DS/4))*4;
    int z   = gid / (DI*DS/4);
    long idx = (long)z*NCHUNK*DI*DS + dn4;
    float4 hin = {0.f,0.f,0.f,0.f};
    for (int c = 0; c < NCHUNK; c++){
        float4 Pv = *(const float4*)(Pbuf + idx);
        float4 Sv = *(const float4*)(Sbuf + idx);
        *(float4*)(Sbuf + idx) = hin;
        hin.x = Pv.x*hin.x + Sv.x;
        hin.y = Pv.y*hin.y + Sv.y;
        hin.z = Pv.z*hin.z + Sv.z;
        hin.w = Pv.w*hin.w + Sv.w;
        idx += (long)DI*DS;
    }
}

// ---------------- pass2: 4 n-states / thread, no z (gating moved to ys_gate) ------
__global__ __launch_bounds__(256) void scan_pass2_kernel(
        const float* __restrict__ xc2, const float* __restrict__ dt2,
        const float* __restrict__ xdbl2,
        const float* __restrict__ Alog_f, const float* __restrict__ Dp_f,
        const float* __restrict__ Alog_b, const float* __restrict__ Dp_b,
        const float* __restrict__ Hbuf,
        float* __restrict__ ys_f, float* __restrict__ ys_b)
{
    int dchunk = blockIdx.x;
    int chunk  = blockIdx.y;
    int z      = blockIdx.z;
    int b = z & 1, dir = z >> 1;
    int tid = threadIdx.x;
    int dl = tid >> 2, nq = tid & 3;
    int dbase = dchunk*DTILE;
    int d = dbase + dl;

    const float* xc = xc2 + (long)dir*NROWS*DI;
    const float* dt = dt2 + (long)dir*NROWS*DI;
    const float* xd = xdbl2 + (long)dir*NROWS*56;
    const float* Alog = dir ? Alog_b : Alog_f;
    const float* Dpp  = dir ? Dp_b   : Dp_f;
    float* ys = dir ? ys_b : ys_f;

    float Av2[4];
    #pragma unroll
    for (int j = 0; j < 4; j++)
        Av2[j] = -__expf(Alog[d*DS + nq*4 + j]) * LOG2E;
    float Dval = Dpp[d];

    __shared__ float sdt[CLEN][DTILE], sxc[CLEN][DTILE], sB[CLEN][16], sC[CLEN][16];
    int c0 = chunk * CLEN;
    for (int e = tid; e < CLEN*16; e += 256){
        int s = e >> 4, q4 = (e & 15)*4;
        long row = (long)b*L_SEQ + c0 + s;
        *(float4*)&sdt[s][q4] = *(const float4*)(dt + row*DI + dbase + q4);
        *(float4*)&sxc[s][q4] = *(const float4*)(xc + row*DI + dbase + q4);
    }
    for (int e = tid; e < CLEN*4; e += 256){
        int s = e >> 2, q4 = (e & 3)*4;
        long row = (long)b*L_SEQ + c0 + s;
        *(float4*)&sB[s][q4] = *(const float4*)(xd + row*56 + DTR + q4);
        *(float4*)&sC[s][q4] = *(const float4*)(xd + row*56 + DTR + DS + q4);
    }
    __syncthreads();

    long idx = (((long)z*NCHUNK + chunk)*DI + d)*DS + nq*4;
    float4 H = *(const float4*)(Hbuf + idx);
    float h0=H.x, h1=H.y, h2=H.z, h3=H.w;

    for (int s = 0; s < CLEN; s++){
        float dtv = sdt[s][dl], xcv = sxc[s][dl];
        float4 Bv = *(float4*)&sB[s][nq*4];
        float4 Cv = *(float4*)&sC[s][nq*4];
        float tmp = dtv*xcv;
        h0 = exp2f(dtv*Av2[0])*h0 + tmp*Bv.x;
        h1 = exp2f(dtv*Av2[1])*h1 + tmp*Bv.y;
        h2 = exp2f(dtv*Av2[2])*h2 + tmp*Bv.z;
        h3 = exp2f(dtv*Av2[3])*h3 + tmp*Bv.w;
        float c = h0*Cv.x + h1*Cv.y + h2*Cv.z + h3*Cv.w;
        c += __shfl_xor(c, 1);
        c += __shfl_xor(c, 2);
        if (nq == 0){
            int p = c0 + s;
            int phys = dir ? (L_SEQ-1-p) : p;
            ys[((long)b*L_SEQ + phys)*DI + d] = c + Dval*xcv;
        }
    }
}

// ---------------- ys gate: (ysf+ysb)*silu(z) -> bf16 -----------------------------
__global__ __launch_bounds__(256) void ys_gate_kernel(
        const float* __restrict__ ysf, const float* __restrict__ ysb,
        const ushort_t* __restrict__ zi, ushort_t* __restrict__ out)
{
    int i4 = (blockIdx.x*256 + threadIdx.x)*4;
    if (i4 >= NROWS*DI) return;
    float4 a = *(const float4*)(ysf + i4);
    float4 bb = *(const float4*)(ysb + i4);
    ushort4 u = *(const ushort4*)(zi + i4);
    ushort4 r;
    {
        float zv = us2f(u.x); float g = zv/(1.f+__expf(-zv));
        r.x = f2us((a.x+bb.x)*g);
    }{
        float zv = us2f(u.y); float g = zv/(1.f+__expf(-zv));
        r.y = f2us((a.y+bb.y)*g);
    }{
        float zv = us2f(u.z); float g = zv/(1.f+__expf(-zv));
        r.z = f2us((a.z+bb.z)*g);
    }{
        float zv = us2f(u.w); float g = zv/(1.f+__expf(-zv));
        r.w = f2us((a.w+bb.w)*g);
    }
    *(ushort4*)(out + i4) = r;
}

// ---------------- final rmsnorm --------------------------------------------------
__global__ __launch_bounds__(128) void rmsnorm_final_kernel(
        const float* __restrict__ res, const float* __restrict__ h,
        const float* __restrict__ w, float* __restrict__ out)
{
    int r = blockIdx.x; int tid = threadIdx.x;
    const float* hr = h + (long)r*DM;
    const float* rr = res + (long)r*DM;
    float v[3]; float ss = 0.f;
    #pragma unroll
    for (int i = 0; i < 3; i++){
        int c = tid + i*128;
        float x = rr[c] + hr[c];
        v[i] = x; ss += x*x;
    }
    #pragma unroll
    for (int off = 32; off; off >>= 1) ss += __shfl_down(ss, off, 64);
    __shared__ float wsum[2];
    if ((tid & 63) == 0) wsum[tid >> 6] = ss;
    __syncthreads();
    float scale = rsqrtf((wsum[0] + wsum[1]) / (float)DM + EPS_);
    #pragma unroll
    for (int i = 0; i < 3; i++){
        int c = tid + i*128;
        out[(long)r*DM + c] = v[i] * scale * w[c];
    }
}

extern "C" void kernel_launch(void* const* d_in, const int* in_sizes, int n_in,
                              void* d_out, int out_size, void* d_ws, size_t ws_size,
                              hipStream_t stream)
{
    const float* x         = (const float*)d_in[0];
    const float* patch_w   = (const float*)d_in[1];
    const float* patch_b   = (const float*)d_in[2];
    const float* pos_embed = (const float*)d_in[3];
    const float* temp_pos  = (const float*)d_in[4];
    const float* in_proj   = (const float*)d_in[5];
    const float* conv_w    = (const float*)d_in[6];
    const float* conv_b    = (const float*)d_in[7];
    const float* xproj_w   = (const float*)d_in[8];
    const float* dt_w      = (const float*)d_in[9];
    const float* dt_b      = (const float*)d_in[10];
    const float* A_log     = (const float*)d_in[11];
    const float* Dp        = (const float*)d_in[12];
    const float* conv_w_b  = (const float*)d_in[13];
    const float* conv_b_b  = (const float*)d_in[14];
    const float* xproj_w_b = (const float*)d_in[15];
    const float* dt_w_b    = (const float*)d_in[16];
    const float* dt_b_b    = (const float*)d_in[17];
    const float* A_log_b   = (const float*)d_in[18];
    const float* Dp_b      = (const float*)d_in[19];
    const float* out_proj  = (const float*)d_in[20];
    const float* norm_w    = (const float*)d_in[21];
    const float* norm_f    = (const float*)d_in[22];

    float* ws = (float*)d_ws;
    size_t off = 0;
    float* hidden   = ws + off; off += (size_t)NROWS*DM;           // 1,204,224
    float* residual = ws + off; off += (size_t)NROWS*DM;
    float* hnormreg = ws + off; off += (size_t)NROWS*DM/2;         // bf16 hnorm; Pbuf head
    float* xireg    = ws + off; off += (size_t)NROWS*DI/2;         // bf16 xi; Pbuf tail
    float* zireg    = ws + off; off += (size_t)NROWS*DI/2;         // bf16 zi; ys_bf alias
    float* xc2      = ws + off; off += (size_t)2*NROWS*DI;         // f32; patches_bf alias
    float* xc2bfreg = ws + off; off += (size_t)NROWS*DI;           // bf16 xc (2 dirs)
    float* xdbl2    = ws + off; off += (size_t)2*NROWS*56;
    float* xdblbf_f = ws + off; off += (size_t)2*NROWS*32/2;
    float* dt2      = ws + off; off += (size_t)2*NROWS*DI;
    float* ysf      = ws + off; off += (size_t)NROWS*DI;
    float* ysb      = ws + off; off += (size_t)NROWS*DI;
    float* Sbuf     = ws + off; off += (size_t)4*NCHUNK*DI*DS;     // 1,572,864
    float* wbf_f    = ws + off; off += (size_t)(WCVT_TOTAL+1)/2;
    float* wpbf_f   = ws + off; off += (size_t)(DM*DI+1)/2;
    // total ~23.8M floats ~95.0 MB

    ushort_t* hnorm_bf   = (ushort_t*)hnormreg;
    ushort_t* xi_bf      = (ushort_t*)xireg;
    ushort_t* zi_bf      = (ushort_t*)zireg;
    ushort_t* ys_bf      = (ushort_t*)zireg;   // alias: ys_gate reads zi[i], writes out[i]
    ushort_t* xc2_bf     = (ushort_t*)xc2bfreg;
    ushort_t* xdbl_bf    = (ushort_t*)xdblbf_f;
    ushort_t* patches_bf = (ushort_t*)xc2;     // dead once conv writes xc2 (layer 0)
    ushort_t* wbf        = (ushort_t*)wbf_f;
    ushort_t* wp_bf      = (ushort_t*)wpbf_f;
    ushort_t* wi_bf  = wbf;
    ushort_t* wo_bf  = wbf + WI_SZ;
    ushort_t* wx_bf  = wbf + WI_SZ + WO_SZ;
    ushort_t* wdt_bf = wbf + WI_SZ + WO_SZ + 2*WX_SZ;
    float* Pbuf = hnormreg;   // 1,572,864 floats over hnorm(602,112)+xi head; both dead by pass1

    hipMemsetAsync(residual, 0, (size_t)NROWS*DM*sizeof(float), stream);

    patchify_kernel<<<(NROWS*768+255)/256, 256, 0, stream>>>(x, patches_bf);
    convert_kernel<<<(DM*DI+255)/256, 256, 0, stream>>>(patch_w, wp_bf, DM*DI);
    gemm_mfma_kernel<<<dim3(DM/64, NROWS/64, 1), 256, 0, stream>>>(
        patches_bf, DI, 0, wp_bf, DI, 0, DI, DM,
        hidden, 0, nullptr, nullptr, 0, 2, patch_b, pos_embed, temp_pos);

    for (int l = 0; l < DEPTH; l++){
        convert_layer_kernel<<<(WCVT_TOTAL+255)/256, 256, 0, stream>>>(
            in_proj + (size_t)l*WI_SZ, out_proj + (size_t)l*WO_SZ,
            xproj_w + (size_t)l*WX_SZ, xproj_w_b + (size_t)l*WX_SZ,
            dt_w + (size_t)l*DI*DTR, dt_w_b + (size_t)l*DI*DTR, wbf);

        rmsnorm_kernel<<<NROWS, 128, 0, stream>>>(residual, hidden, hnorm_bf,
                                                  norm_w + (size_t)l*DM);
        // in_proj -> xi_bf, zi_bf
        gemm_mfma_kernel<<<dim3(2*DI/64, NROWS/64, 1), 256, 0, stream>>>(
            hnorm_bf, DM, 0, wi_bf, DM, 0, DM, 2*DI,
            nullptr, 0, xi_bf, zi_bf, 0, 1, nullptr, nullptr, nullptr);

        conv_kernel<<<(2*NROWS*192+255)/256, 256, 0, stream>>>(
            xi_bf, conv_w + (size_t)l*DI*KCONV, conv_b + (size_t)l*DI,
            conv_w_b + (size_t)l*DI*KCONV, conv_b_b + (size_t)l*DI, xc2, xc2_bf);

        // xproj fwd+bwd: xc2_bf x wx^T -> xdbl2 f32 + xdbl_bf (K-padded bf16)
        gemm_mfma_kernel<<<dim3(1, NROWS/64, 2), 256, 0, stream>>>(
            xc2_bf, DI, (long)NROWS*DI, wx_bf, DI, WX_SZ, DI, 64,
            xdbl2, (long)NROWS*56, xdbl_bf, nullptr, (long)NROWS*32, 4,
            nullptr, nullptr, nullptr);

        // dt fwd+bwd: xdbl_bf(3136,32) x wdt(768,32)^T + bias, softplus
        gemm_mfma_kernel<<<dim3(DI/64, NROWS/64, 2), 256, 0, stream>>>(
            xdbl_bf, 32, (long)NROWS*32, wdt_bf, 32, WDT_SZ, 32, DI,
            dt2, (long)NROWS*DI, nullptr, nullptr, 0, 3,
            dt_b + (size_t)l*DI, dt_b_b + (size_t)l*DI, nullptr);

        scan_pass1_kernel<<<dim3(NDC, NCHUNK, 4), 256, 0, stream>>>(
            xc2, dt2, xdbl2, A_log + (size_t)l*DI*DS, A_log_b + (size_t)l*DI*DS,
            Pbuf, Sbuf);
        scan_combine_kernel<<<(4*DI*DS/4+255)/256, 256, 0, stream>>>(Pbuf, Sbuf);
        scan_pass2_kernel<<<dim3(NDC, NCHUNK, 4), 256, 0, stream>>>(
            xc2, dt2, xdbl2,
            A_log + (size_t)l*DI*DS, Dp + (size_t)l*DI,
            A_log_b + (size_t)l*DI*DS, Dp_b + (size_t)l*DI,
            Sbuf, ysf, ysb);

        ys_gate_kernel<<<(NROWS*DI/4+255)/256, 256, 0, stream>>>(ysf, ysb, zi_bf, ys_bf);

        // out_proj: ys_bf x wo^T -> hidden
        gemm_mfma_kernel<<<dim3(DM/64, NROWS/64, 1), 256, 0, stream>>>(
            ys_bf, DI, 0, wo_bf, DI, 0, DI, DM,
            hidden, 0, nullptr, nullptr, 0, 0, nullptr, nullptr, nullptr);
    }

    rmsnorm_final_kernel<<<NROWS, 128, 0, stream>>>(residual, hidden,
                                                    norm_f, (float*)d_out);
}

// Round 7
// 5454.303 us; speedup vs baseline: 1.4712x; 1.0255x over previous
//
#include <hip/hip_runtime.h>
#include <hip/hip_bf16.h>

typedef unsigned short ushort_t;
typedef short bf16x8 __attribute__((ext_vector_type(8)));
typedef float f32x4  __attribute__((ext_vector_type(4)));

#define BATCH   2
#define FRAMES  8
#define GRID_   14
#define NTOK    196
#define PS      16
#define IMG     224
#define L_SEQ   1568
#define DM      384
#define DI      768
#define DTR     24
#define DS      16
#define DEPTH   24
#define KCONV   4
#define NROWS   (BATCH*L_SEQ)   // 3136
#define EPS_    1e-5f
#define NCHUNK  32
#define CLEN    49              // 32*49 = 1568
#define DTILE   64
#define NDC     (DI/DTILE)      // 12
#define LOG2E   1.4426950408889634f

__device__ __forceinline__ ushort_t f2us(float f){
    __hip_bfloat16 h = __float2bfloat16(f);
    return *reinterpret_cast<ushort_t*>(&h);
}
__device__ __forceinline__ float us2f(ushort_t u){
    return __uint_as_float(((unsigned int)u) << 16);
}

// ---------------- patchify ------------------------------------------------------
__global__ __launch_bounds__(256) void patchify_kernel(const float* __restrict__ x,
                                                       ushort_t* __restrict__ patches){
    int idx = blockIdx.x*256 + threadIdx.x;
    if (idx >= NROWS*768) return;
    int k   = idx % 768;
    int r   = idx / 768;
    int tok = r % NTOK;
    int bt  = r / NTOK;
    int t = bt % FRAMES, b = bt / FRAMES;
    int gy = tok / GRID_, gx = tok % GRID_;
    int c = k / 256; int rem = k % 256; int py = rem/16, px = rem%16;
    long xo = (((long)(b*3 + c)*FRAMES + t)*IMG + (gy*PS+py))*IMG + (gx*PS+px);
    patches[idx] = f2us(x[xo]);
}

__global__ __launch_bounds__(256) void convert_kernel(const float* __restrict__ in,
                                                      ushort_t* __restrict__ out, int n){
    int i = blockIdx.x*256 + threadIdx.x;
    if (i < n) out[i] = f2us(in[i]);
}

// ---------------- per-layer weight conversion ------------------------------------
#define WI_SZ  (2*DI*DM)
#define WO_SZ  (DM*DI)
#define WX_SZ  (56*DI)
#define WDT_SZ (DI*32)
#define WCVT_TOTAL (WI_SZ + WO_SZ + 2*WX_SZ + 2*WDT_SZ)

__global__ __launch_bounds__(256) void convert_layer_kernel(
        const float* __restrict__ wi, const float* __restrict__ wo,
        const float* __restrict__ wxf, const float* __restrict__ wxb,
        const float* __restrict__ wdtf, const float* __restrict__ wdtb,
        ushort_t* __restrict__ out)
{
    int gid = blockIdx.x*256 + threadIdx.x;
    if (gid >= WCVT_TOTAL) return;
    float v;
    if (gid < WI_SZ)                       v = wi[gid];
    else if (gid < WI_SZ+WO_SZ)            v = wo[gid - WI_SZ];
    else if (gid < WI_SZ+WO_SZ+WX_SZ)      v = wxf[gid - WI_SZ - WO_SZ];
    else if (gid < WI_SZ+WO_SZ+2*WX_SZ)    v = wxb[gid - WI_SZ - WO_SZ - WX_SZ];
    else if (gid < WI_SZ+WO_SZ+2*WX_SZ+WDT_SZ){
        int i = gid - (WI_SZ+WO_SZ+2*WX_SZ);
        int rr = i >> 5, c = i & 31;
        v = (c < DTR) ? wdtf[rr*DTR + c] : 0.f;
    } else {
        int i = gid - (WI_SZ+WO_SZ+2*WX_SZ+WDT_SZ);
        int rr = i >> 5, c = i & 31;
        v = (c < DTR) ? wdtb[rr*DTR + c] : 0.f;
    }
    out[gid] = f2us(v);
}

// ---------------- MFMA GEMM, bf16 A: C[M,N] = A[M,K] * W[N,K]^T -------------------
// modes: 0 plain f32; 1 in_proj split -> bf16 xi/zi; 2 patch epilogue;
//        3 dt softplus + bias(z-sel) -> bf16; 4 xproj dual (f32 56 + bf16 32 pad0)
__global__ __launch_bounds__(256) void gemm_mfma_kernel(
        const ushort_t* __restrict__ A, int lda, long strideA,
        const ushort_t* __restrict__ W, int ldw, long strideW,
        int K, int N,
        float* __restrict__ out0, long strideO0,
        ushort_t* __restrict__ outb0, ushort_t* __restrict__ outb1, long strideOb,
        int mode,
        const float* __restrict__ aux0, const float* __restrict__ aux1,
        const float* __restrict__ aux2)
{
    int z = blockIdx.z;
    A += (long)z * strideA;
    W += (long)z * strideW;
    if (out0)  out0  += (long)z * strideO0;
    if (outb0) outb0 += (long)z * strideOb;

    int tid  = threadIdx.x;
    int wave = tid >> 6, lane = tid & 63;
    int l15 = lane & 15, quad = lane >> 4;
    int m0 = blockIdx.y * 64, n0 = blockIdx.x * 64;

    const ushort_t* wp  = W + (long)(n0 + wave*16 + l15)*ldw + quad*8;
    const ushort_t* ap0 = A + (long)(m0 + l15)*lda + quad*8;

    f32x4 acc[4] = {f32x4{0,0,0,0}, f32x4{0,0,0,0}, f32x4{0,0,0,0}, f32x4{0,0,0,0}};

    for (int k0 = 0; k0 < K; k0 += 32){
        bf16x8 bfrag = *reinterpret_cast<const bf16x8*>(wp + k0);
        #pragma unroll
        for (int mt = 0; mt < 4; mt++){
            bf16x8 afrag = *reinterpret_cast<const bf16x8*>(ap0 + (long)mt*16*lda + k0);
            acc[mt] = __builtin_amdgcn_mfma_f32_16x16x32_bf16(afrag, bfrag, acc[mt], 0, 0, 0);
        }
    }

    int cn = n0 + wave*16 + l15;
    #pragma unroll
    for (int mt = 0; mt < 4; mt++){
        #pragma unroll
        for (int r = 0; r < 4; r++){
            int row = m0 + mt*16 + quad*4 + r;
            float v = acc[mt][r];
            if (mode == 0){
                out0[(long)row*N + cn] = v;
            } else if (mode == 1){
                if (cn < DI) outb0[(long)row*DI + cn] = f2us(v);
                else         outb1[(long)row*DI + cn - DI] = f2us(v);
            } else if (mode == 2){
                int tok = row % NTOK, t = (row/NTOK) % FRAMES;
                out0[(long)row*N + cn] = v + aux0[cn] + aux1[tok*DM+cn] + aux2[t*DM+cn];
            } else if (mode == 3){
                const float* bias = z ? aux1 : aux0;
                float xs = v + bias[cn];
                float sp = (xs > 20.f) ? xs : log1pf(__expf(xs));
                outb0[(long)row*N + cn] = f2us(sp);
            } else { // mode 4
                if (cn < 56) out0[(long)row*56 + cn] = v;
                if (cn < 32) outb0[(long)row*32 + cn] = f2us(cn < DTR ? v : 0.f);
            }
        }
    }
}

// ---------------- rmsnorm (+ residual add), bf16 out -----------------------------
__global__ __launch_bounds__(128) void rmsnorm_kernel(
        float* __restrict__ res, const float* __restrict__ h,
        ushort_t* __restrict__ outb, const float* __restrict__ w)
{
    int r = blockIdx.x; int tid = threadIdx.x;
    const float* hr = h + (long)r*DM;
    float* rr = res + (long)r*DM;
    float v[3]; float ss = 0.f;
    #pragma unroll
    for (int i = 0; i < 3; i++){
        int c = tid + i*128;
        float x = rr[c] + hr[c];
        rr[c] = x; v[i] = x; ss += x*x;
    }
    #pragma unroll
    for (int off = 32; off; off >>= 1) ss += __shfl_down(ss, off, 64);
    __shared__ float wsum[2];
    if ((tid & 63) == 0) wsum[tid >> 6] = ss;
    __syncthreads();
    float scale = rsqrtf((wsum[0] + wsum[1]) / (float)DM + EPS_);
    #pragma unroll
    for (int i = 0; i < 3; i++){
        int c = tid + i*128;
        outb[(long)r*DM + c] = f2us(v[i] * scale * w[c]);
    }
}

// ---------------- depthwise causal conv + silu -> bf16 ---------------------------
__global__ __launch_bounds__(256) void conv_kernel(
        const ushort_t* __restrict__ xi,
        const float* __restrict__ cw_f, const float* __restrict__ cb_f,
        const float* __restrict__ cw_b, const float* __restrict__ cb_b,
        ushort_t* __restrict__ xcb)
{
    int vidx = blockIdx.x*256 + threadIdx.x;
    if (vidx >= 2*NROWS*192) return;
    int dq = vidx % 192; int d4 = dq*4;
    int r2 = vidx / 192;
    int dir = r2 / NROWS;
    int rr  = r2 % NROWS;
    int b = rr / L_SEQ, p = rr % L_SEQ;
    const float* cw = dir ? cw_b : cw_f;
    const float* cb = dir ? cb_b : cb_f;
    float w[4][4];
    #pragma unroll
    for (int dd = 0; dd < 4; dd++){
        float4 wv = *(const float4*)(cw + (d4+dd)*KCONV);
        w[dd][0]=wv.x; w[dd][1]=wv.y; w[dd][2]=wv.z; w[dd][3]=wv.w;
    }
    float4 acc = *(const float4*)(cb + d4);
    #pragma unroll
    for (int j = 0; j < KCONV; j++){
        int pp = p - (KCONV-1) + j;
        if (pp >= 0){
            int phys = dir ? (L_SEQ-1-pp) : pp;
            ushort4 u = *(const ushort4*)(xi + ((long)b*L_SEQ + phys)*DI + d4);
            acc.x += w[0][j]*us2f(u.x);
            acc.y += w[1][j]*us2f(u.y);
            acc.z += w[2][j]*us2f(u.z);
            acc.w += w[3][j]*us2f(u.w);
        }
    }
    ushort4 ob;
    ob.x = f2us(acc.x/(1.f+__expf(-acc.x)));
    ob.y = f2us(acc.y/(1.f+__expf(-acc.y)));
    ob.z = f2us(acc.z/(1.f+__expf(-acc.z)));
    ob.w = f2us(acc.w/(1.f+__expf(-acc.w)));
    *(ushort4*)(xcb + (long)r2*DI + d4) = ob;
}

// ---------------- chunked selective scan: pass1 (bf16 inputs) ---------------------
__global__ __launch_bounds__(256) void scan_pass1_kernel(
        const ushort_t* __restrict__ xcb, const ushort_t* __restrict__ dtb,
        const float* __restrict__ xdbl2,
        const float* __restrict__ Alog_f, const float* __restrict__ Alog_b,
        float* __restrict__ Pbuf, float* __restrict__ Sbuf)
{
    int dchunk = blockIdx.x;    // 12
    int chunk  = blockIdx.y;    // 32
    int z      = blockIdx.z;    // 4
    int b = z & 1, dir = z >> 1;
    int tid = threadIdx.x;
    int dl = tid >> 2, nq = tid & 3;
    int dbase = dchunk*DTILE;
    int d = dbase + dl;

    const ushort_t* xc = xcb + (long)dir*NROWS*DI;
    const ushort_t* dt = dtb + (long)dir*NROWS*DI;
    const float* xd = xdbl2 + (long)dir*NROWS*56;
    const float* Alog = dir ? Alog_b : Alog_f;

    float Av2[4];
    #pragma unroll
    for (int j = 0; j < 4; j++)
        Av2[j] = -__expf(Alog[d*DS + nq*4 + j]) * LOG2E;

    __shared__ float sdt[CLEN][DTILE], sxc[CLEN][DTILE], sB[CLEN][16];
    int c0 = chunk * CLEN;
    for (int e = tid; e < CLEN*16; e += 256){
        int s = e >> 4, q4 = (e & 15)*4;
        long row = (long)b*L_SEQ + c0 + s;
        ushort4 du = *(const ushort4*)(dt + row*DI + dbase + q4);
        ushort4 xu = *(const ushort4*)(xc + row*DI + dbase + q4);
        float4 df; df.x=us2f(du.x); df.y=us2f(du.y); df.z=us2f(du.z); df.w=us2f(du.w);
        float4 xf; xf.x=us2f(xu.x); xf.y=us2f(xu.y); xf.z=us2f(xu.z); xf.w=us2f(xu.w);
        *(float4*)&sdt[s][q4] = df;
        *(float4*)&sxc[s][q4] = xf;
    }
    for (int e = tid; e < CLEN*4; e += 256){
        int s = e >> 2, q4 = (e & 3)*4;
        long row = (long)b*L_SEQ + c0 + s;
        *(float4*)&sB[s][q4] = *(const float4*)(xd + row*56 + DTR + q4);
    }
    __syncthreads();

    float h0=0.f,h1=0.f,h2=0.f,h3=0.f, dts=0.f;
    for (int s = 0; s < CLEN; s++){
        float dtv = sdt[s][dl], xcv = sxc[s][dl];
        float4 Bv = *(float4*)&sB[s][nq*4];
        float tmp = dtv*xcv;
        dts += dtv;
        h0 = exp2f(dtv*Av2[0])*h0 + tmp*Bv.x;
        h1 = exp2f(dtv*Av2[1])*h1 + tmp*Bv.y;
        h2 = exp2f(dtv*Av2[2])*h2 + tmp*Bv.z;
        h3 = exp2f(dtv*Av2[3])*h3 + tmp*Bv.w;
    }
    long idx = (((long)z*NCHUNK + chunk)*DI + d)*DS + nq*4;
    float4 P; P.x=exp2f(Av2[0]*dts); P.y=exp2f(Av2[1]*dts);
    P.z=exp2f(Av2[2]*dts); P.w=exp2f(Av2[3]*dts);
    float4 S; S.x=h0; S.y=h1; S.z=h2; S.w=h3;
    *(float4*)(Pbuf + idx) = P;
    *(float4*)(Sbuf + idx) = S;
}

// ---------------- combine: Sbuf -> Hin in place, float4 lanes ---------------------
__global__ __launch_bounds__(256) void scan_combine_kernel(
        const float* __restrict__ Pbuf, float* __restrict__ Sbuf)
{
    int gid = blockIdx.x*256 + threadIdx.x;     // over 4*DI*DS/4 = 12288
    if (gid >= 4*DI*DS/4) return;
    int dn4 = (gid % (DI*DS/4))*4;
    int z   = gid / (DI*DS/4);
    long idx = (long)z*NCHUNK*DI*DS + dn4;
    float4 hin = {0.f,0.f,0.f,0.f};
    for (int c = 0; c < NCHUNK; c++){
        float4 Pv = *(const float4*)(Pbuf + idx);
        float4 Sv = *(const float4*)(Sbuf + idx);
        *(float4*)(Sbuf + idx) = hin;
        hin.x = Pv.x*hin.x + Sv.x;
        hin.y = Pv.y*hin.y + Sv.y;
        hin.z = Pv.z*hin.z + Sv.z;
        hin.w = Pv.w*hin.w + Sv.w;
        idx += (long)DI*DS;
    }
}

// ---------------- pass2: bf16 in, bf16 ys out ------------------------------------
__global__ __launch_bounds__(256) void scan_pass2_kernel(
        const ushort_t* __restrict__ xcb, const ushort_t* __restrict__ dtb,
        const float* __restrict__ xdbl2,
        const float* __restrict__ Alog_f, const float* __restrict__ Dp_f,
        const float* __restrict__ Alog_b, const float* __restrict__ Dp_b,
        const float* __restrict__ Hbuf,
        ushort_t* __restrict__ ys_f, ushort_t* __restrict__ ys_b)
{
    int dchunk = blockIdx.x;
    int chunk  = blockIdx.y;
    int z      = blockIdx.z;
    int b = z & 1, dir = z >> 1;
    int tid = threadIdx.x;
    int dl = tid >> 2, nq = tid & 3;
    int dbase = dchunk*DTILE;
    int d = dbase + dl;

    const ushort_t* xc = xcb + (long)dir*NROWS*DI;
    const ushort_t* dt = dtb + (long)dir*NROWS*DI;
    const float* xd = xdbl2 + (long)dir*NROWS*56;
    const float* Alog = dir ? Alog_b : Alog_f;
    const float* Dpp  = dir ? Dp_b   : Dp_f;
    ushort_t* ys = dir ? ys_b : ys_f;

    float Av2[4];
    #pragma unroll
    for (int j = 0; j < 4; j++)
        Av2[j] = -__expf(Alog[d*DS + nq*4 + j]) * LOG2E;
    float Dval = Dpp[d];

    __shared__ float sdt[CLEN][DTILE], sxc[CLEN][DTILE], sB[CLEN][16], sC[CLEN][16];
    int c0 = chunk * CLEN;
    for (int e = tid; e < CLEN*16; e += 256){
        int s = e >> 4, q4 = (e & 15)*4;
        long row = (long)b*L_SEQ + c0 + s;
        ushort4 du = *(const ushort4*)(dt + row*DI + dbase + q4);
        ushort4 xu = *(const ushort4*)(xc + row*DI + dbase + q4);
        float4 df; df.x=us2f(du.x); df.y=us2f(du.y); df.z=us2f(du.z); df.w=us2f(du.w);
        float4 xf; xf.x=us2f(xu.x); xf.y=us2f(xu.y); xf.z=us2f(xu.z); xf.w=us2f(xu.w);
        *(float4*)&sdt[s][q4] = df;
        *(float4*)&sxc[s][q4] = xf;
    }
    for (int e = tid; e < CLEN*4; e += 256){
        int s = e >> 2, q4 = (e & 3)*4;
        long row = (long)b*L_SEQ + c0 + s;
        *(float4*)&sB[s][q4] = *(const float4*)(xd + row*56 + DTR + q4);
        *(float4*)&sC[s][q4] = *(const float4*)(xd + row*56 + DTR + DS + q4);
    }
    __syncthreads();

    long idx = (((long)z*NCHUNK + chunk)*DI + d)*DS + nq*4;
    float4 H = *(const float4*)(Hbuf + idx);
    float h0=H.x, h1=H.y, h2=H.z, h3=H.w;

    for (int s = 0; s < CLEN; s++){
        float dtv = sdt[s][dl], xcv = sxc[s][dl];
        float4 Bv = *(float4*)&sB[s][nq*4];
        float4 Cv = *(float4*)&sC[s][nq*4];
        float tmp = dtv*xcv;
        h0 = exp2f(dtv*Av2[0])*h0 + tmp*Bv.x;
        h1 = exp2f(dtv*Av2[1])*h1 + tmp*Bv.y;
        h2 = exp2f(dtv*Av2[2])*h2 + tmp*Bv.z;
        h3 = exp2f(dtv*Av2[3])*h3 + tmp*Bv.w;
        float c = h0*Cv.x + h1*Cv.y + h2*Cv.z + h3*Cv.w;
        c += __shfl_xor(c, 1);
        c += __shfl_xor(c, 2);
        if (nq == 0){
            int p = c0 + s;
            int phys = dir ? (L_SEQ-1-p) : p;
            ys[((long)b*L_SEQ + phys)*DI + d] = f2us(c + Dval*xcv);
        }
    }
}

// ---------------- ys gate: (ysf+ysb)*silu(z) -> bf16 -----------------------------
__global__ __launch_bounds__(256) void ys_gate_kernel(
        const ushort_t* __restrict__ ysf, const ushort_t* __restrict__ ysb,
        const ushort_t* __restrict__ zi, ushort_t* __restrict__ out)
{
    int i4 = (blockIdx.x*256 + threadIdx.x)*4;
    if (i4 >= NROWS*DI) return;
    ushort4 a = *(const ushort4*)(ysf + i4);
    ushort4 bb = *(const ushort4*)(ysb + i4);
    ushort4 u = *(const ushort4*)(zi + i4);
    ushort4 r;
    {
        float zv = us2f(u.x); float g = zv/(1.f+__expf(-zv));
        r.x = f2us((us2f(a.x)+us2f(bb.x))*g);
    }{
        float zv = us2f(u.y); float g = zv/(1.f+__expf(-zv));
        r.y = f2us((us2f(a.y)+us2f(bb.y))*g);
    }{
        float zv = us2f(u.z); float g = zv/(1.f+__expf(-zv));
        r.z = f2us((us2f(a.z)+us2f(bb.z))*g);
    }{
        float zv = us2f(u.w); float g = zv/(1.f+__expf(-zv));
        r.w = f2us((us2f(a.w)+us2f(bb.w))*g);
    }
    *(ushort4*)(out + i4) = r;
}

// ---------------- final rmsnorm --------------------------------------------------
__global__ __launch_bounds__(128) void rmsnorm_final_kernel(
        const float* __restrict__ res, const float* __restrict__ h,
        const float* __restrict__ w, float* __restrict__ out)
{
    int r = blockIdx.x; int tid = threadIdx.x;
    const float* hr = h + (long)r*DM;
    const float* rr = res + (long)r*DM;
    float v[3]; float ss = 0.f;
    #pragma unroll
    for (int i = 0; i < 3; i++){
        int c = tid + i*128;
        float x = rr[c] + hr[c];
        v[i] = x; ss += x*x;
    }
    #pragma unroll
    for (int off = 32; off; off >>= 1) ss += __shfl_down(ss, off, 64);
    __shared__ float wsum[2];
    if ((tid & 63) == 0) wsum[tid >> 6] = ss;
    __syncthreads();
    float scale = rsqrtf((wsum[0] + wsum[1]) / (float)DM + EPS_);
    #pragma unroll
    for (int i = 0; i < 3; i++){
        int c = tid + i*128;
        out[(long)r*DM + c] = v[i] * scale * w[c];
    }
}

extern "C" void kernel_launch(void* const* d_in, const int* in_sizes, int n_in,
                              void* d_out, int out_size, void* d_ws, size_t ws_size,
                              hipStream_t stream)
{
    const float* x         = (const float*)d_in[0];
    const float* patch_w   = (const float*)d_in[1];
    const float* patch_b   = (const float*)d_in[2];
    const float* pos_embed = (const float*)d_in[3];
    const float* temp_pos  = (const float*)d_in[4];
    const float* in_proj   = (const float*)d_in[5];
    const float* conv_w    = (const float*)d_in[6];
    const float* conv_b    = (const float*)d_in[7];
    const float* xproj_w   = (const float*)d_in[8];
    const float* dt_w      = (const float*)d_in[9];
    const float* dt_b      = (const float*)d_in[10];
    const float* A_log     = (const float*)d_in[11];
    const float* Dp        = (const float*)d_in[12];
    const float* conv_w_b  = (const float*)d_in[13];
    const float* conv_b_b  = (const float*)d_in[14];
    const float* xproj_w_b = (const float*)d_in[15];
    const float* dt_w_b    = (const float*)d_in[16];
    const float* dt_b_b    = (const float*)d_in[17];
    const float* A_log_b   = (const float*)d_in[18];
    const float* Dp_b      = (const float*)d_in[19];
    const float* out_proj  = (const float*)d_in[20];
    const float* norm_w    = (const float*)d_in[21];
    const float* norm_f    = (const float*)d_in[22];

    float* ws = (float*)d_ws;
    size_t off = 0;
    float* hidden   = ws + off; off += (size_t)NROWS*DM;           // 1,204,224
    float* residual = ws + off; off += (size_t)NROWS*DM;
    float* hnormreg = ws + off; off += (size_t)NROWS*DM/2;         // bf16 hnorm; Pbuf head
    float* xireg    = ws + off; off += (size_t)NROWS*DI/2;         // bf16 xi; Pbuf tail
    float* zireg    = ws + off; off += (size_t)NROWS*DI/2;         // bf16 zi; ys_bf alias
    float* xc2bfreg = ws + off; off += (size_t)NROWS*DI;           // bf16 xc, 2 dirs
    float* xdbl2    = ws + off; off += (size_t)2*NROWS*56;
    float* xdblbf_f = ws + off; off += (size_t)2*NROWS*32/2;
    float* dt2bfreg = ws + off; off += (size_t)NROWS*DI;           // bf16 dt, 2 dirs; patches alias
    float* ysfbfreg = ws + off; off += (size_t)NROWS*DI/2;         // bf16 ysf
    float* ysbbfreg = ws + off; off += (size_t)NROWS*DI/2;         // bf16 ysb
    float* Sbuf     = ws + off; off += (size_t)4*NCHUNK*DI*DS;     // 1,572,864
    float* wbf_f    = ws + off; off += (size_t)(WCVT_TOTAL+1)/2;
    float* wpbf_f   = ws + off; off += (size_t)(DM*DI+1)/2;
    // total ~15.3M floats ~61 MB

    ushort_t* hnorm_bf   = (ushort_t*)hnormreg;
    ushort_t* xi_bf      = (ushort_t*)xireg;
    ushort_t* zi_bf      = (ushort_t*)zireg;
    ushort_t* ys_bf      = (ushort_t*)zireg;   // gate reads zi[i], writes out[i]: safe
    ushort_t* xc2_bf     = (ushort_t*)xc2bfreg;
    ushort_t* xdbl_bf    = (ushort_t*)xdblbf_f;
    ushort_t* dt2_bf     = (ushort_t*)dt2bfreg;
    ushort_t* ysf_bf     = (ushort_t*)ysfbfreg;
    ushort_t* ysb_bf     = (ushort_t*)ysbbfreg;
    ushort_t* patches_bf = (ushort_t*)dt2bfreg;  // dead before dt GEMM of layer 0
    ushort_t* wbf        = (ushort_t*)wbf_f;
    ushort_t* wp_bf      = (ushort_t*)wpbf_f;
    ushort_t* wi_bf  = wbf;
    ushort_t* wo_bf  = wbf + WI_SZ;
    ushort_t* wx_bf  = wbf + WI_SZ + WO_SZ;
    ushort_t* wdt_bf = wbf + WI_SZ + WO_SZ + 2*WX_SZ;
    float* Pbuf = hnormreg;   // 1,572,864 floats over hnorm(602,112)+xi(1,204,224); both dead by pass1

    hipMemsetAsync(residual, 0, (size_t)NROWS*DM*sizeof(float), stream);

    patchify_kernel<<<(NROWS*768+255)/256, 256, 0, stream>>>(x, patches_bf);
    convert_kernel<<<(DM*DI+255)/256, 256, 0, stream>>>(patch_w, wp_bf, DM*DI);
    gemm_mfma_kernel<<<dim3(DM/64, NROWS/64, 1), 256, 0, stream>>>(
        patches_bf, DI, 0, wp_bf, DI, 0, DI, DM,
        hidden, 0, nullptr, nullptr, 0, 2, patch_b, pos_embed, temp_pos);

    for (int l = 0; l < DEPTH; l++){
        convert_layer_kernel<<<(WCVT_TOTAL+255)/256, 256, 0, stream>>>(
            in_proj + (size_t)l*WI_SZ, out_proj + (size_t)l*WO_SZ,
            xproj_w + (size_t)l*WX_SZ, xproj_w_b + (size_t)l*WX_SZ,
            dt_w + (size_t)l*DI*DTR, dt_w_b + (size_t)l*DI*DTR, wbf);

        rmsnorm_kernel<<<NROWS, 128, 0, stream>>>(residual, hidden, hnorm_bf,
                                                  norm_w + (size_t)l*DM);
        // in_proj -> xi_bf, zi_bf
        gemm_mfma_kernel<<<dim3(2*DI/64, NROWS/64, 1), 256, 0, stream>>>(
            hnorm_bf, DM, 0, wi_bf, DM, 0, DM, 2*DI,
            nullptr, 0, xi_bf, zi_bf, 0, 1, nullptr, nullptr, nullptr);

        conv_kernel<<<(2*NROWS*192+255)/256, 256, 0, stream>>>(
            xi_bf, conv_w + (size_t)l*DI*KCONV, conv_b + (size_t)l*DI,
            conv_w_b + (size_t)l*DI*KCONV, conv_b_b + (size_t)l*DI, xc2_bf);

        // xproj fwd+bwd: xc2_bf x wx^T -> xdbl2 f32 + xdbl_bf (K-padded bf16)
        gemm_mfma_kernel<<<dim3(1, NROWS/64, 2), 256, 0, stream>>>(
            xc2_bf, DI, (long)NROWS*DI, wx_bf, DI, WX_SZ, DI, 64,
            xdbl2, (long)NROWS*56, xdbl_bf, nullptr, (long)NROWS*32, 4,
            nullptr, nullptr, nullptr);

        // dt fwd+bwd: xdbl_bf(3136,32) x wdt(768,32)^T + bias, softplus -> bf16
        gemm_mfma_kernel<<<dim3(DI/64, NROWS/64, 2), 256, 0, stream>>>(
            xdbl_bf, 32, (long)NROWS*32, wdt_bf, 32, WDT_SZ, 32, DI,
            nullptr, 0, dt2_bf, nullptr, (long)NROWS*DI, 3,
            dt_b + (size_t)l*DI, dt_b_b + (size_t)l*DI, nullptr);

        scan_pass1_kernel<<<dim3(NDC, NCHUNK, 4), 256, 0, stream>>>(
            xc2_bf, dt2_bf, xdbl2, A_log + (size_t)l*DI*DS, A_log_b + (size_t)l*DI*DS,
            Pbuf, Sbuf);
        scan_combine_kernel<<<(4*DI*DS/4+255)/256, 256, 0, stream>>>(Pbuf, Sbuf);
        scan_pass2_kernel<<<dim3(NDC, NCHUNK, 4), 256, 0, stream>>>(
            xc2_bf, dt2_bf, xdbl2,
            A_log + (size_t)l*DI*DS, Dp + (size_t)l*DI,
            A_log_b + (size_t)l*DI*DS, Dp_b + (size_t)l*DI,
            Sbuf, ysf_bf, ysb_bf);

        ys_gate_kernel<<<(NROWS*DI/4+255)/256, 256, 0, stream>>>(ysf_bf, ysb_bf, zi_bf, ys_bf);

        // out_proj: ys_bf x wo^T -> hidden
        gemm_mfma_kernel<<<dim3(DM/64, NROWS/64, 1), 256, 0, stream>>>(
            ys_bf, DI, 0, wo_bf, DI, 0, DI, DM,
            hidden, 0, nullptr, nullptr, 0, 0, nullptr, nullptr, nullptr);
    }

    rmsnorm_final_kernel<<<NROWS, 128, 0, stream>>>(residual, hidden,
                                                    norm_f, (float*)d_out);
}

// Round 8
// 5172.431 us; speedup vs baseline: 1.5514x; 1.0545x over previous
//
#include <hip/hip_runtime.h>
#include <hip/hip_bf16.h>

typedef unsigned short ushort_t;
typedef short bf16x8 __attribute__((ext_vector_type(8)));
typedef float f32x4  __attribute__((ext_vector_type(4)));

#define BATCH   2
#define FRAMES  8
#define GRID_   14
#define NTOK    196
#define PS      16
#define IMG     224
#define L_SEQ   1568
#define DM      384
#define DI      768
#define DTR     24
#define DS      16
#define DEPTH   24
#define KCONV   4
#define NROWS   (BATCH*L_SEQ)   // 3136
#define EPS_    1e-5f
#define NCHUNK  32
#define CLEN    49              // 32*49 = 1568
#define DTILE   64
#define NDC     (DI/DTILE)      // 12
#define LOG2E   1.4426950408889634f

__device__ __forceinline__ ushort_t f2us(float f){
    __hip_bfloat16 h = __float2bfloat16(f);
    return *reinterpret_cast<ushort_t*>(&h);
}
__device__ __forceinline__ float us2f(ushort_t u){
    return __uint_as_float(((unsigned int)u) << 16);
}

// ---------------- patchify ------------------------------------------------------
__global__ __launch_bounds__(256) void patchify_kernel(const float* __restrict__ x,
                                                       ushort_t* __restrict__ patches){
    int idx = blockIdx.x*256 + threadIdx.x;
    if (idx >= NROWS*768) return;
    int k   = idx % 768;
    int r   = idx / 768;
    int tok = r % NTOK;
    int bt  = r / NTOK;
    int t = bt % FRAMES, b = bt / FRAMES;
    int gy = tok / GRID_, gx = tok % GRID_;
    int c = k / 256; int rem = k % 256; int py = rem/16, px = rem%16;
    long xo = (((long)(b*3 + c)*FRAMES + t)*IMG + (gy*PS+py))*IMG + (gx*PS+px);
    patches[idx] = f2us(x[xo]);
}

__global__ __launch_bounds__(256) void convert_kernel(const float* __restrict__ in,
                                                      ushort_t* __restrict__ out, int n){
    int i = blockIdx.x*256 + threadIdx.x;
    if (i < n) out[i] = f2us(in[i]);
}

// ---------------- grouped weight conversion (G layers per dispatch) --------------
#define WI_SZ  (2*DI*DM)
#define WO_SZ  (DM*DI)
#define WX_SZ  (56*DI)
#define WDT_SZ (DI*32)
#define WCVT_TOTAL (WI_SZ + WO_SZ + 2*WX_SZ + 2*WDT_SZ)   // 1,019,904

__global__ __launch_bounds__(256) void convert_group_kernel(
        const float* __restrict__ wi, const float* __restrict__ wo,
        const float* __restrict__ wxf, const float* __restrict__ wxb,
        const float* __restrict__ wdtf, const float* __restrict__ wdtb,
        ushort_t* __restrict__ out, int l0, int count)
{
    long gid = (long)blockIdx.x*256 + threadIdx.x;
    if (gid >= (long)count*WCVT_TOTAL) return;
    int ly = (int)(gid / WCVT_TOTAL);
    int r  = (int)(gid % WCVT_TOTAL);
    int l  = l0 + ly;
    float v;
    if (r < WI_SZ)                       v = wi[(long)l*WI_SZ + r];
    else if (r < WI_SZ+WO_SZ)            v = wo[(long)l*WO_SZ + r - WI_SZ];
    else if (r < WI_SZ+WO_SZ+WX_SZ)      v = wxf[(long)l*WX_SZ + r - WI_SZ - WO_SZ];
    else if (r < WI_SZ+WO_SZ+2*WX_SZ)    v = wxb[(long)l*WX_SZ + r - WI_SZ - WO_SZ - WX_SZ];
    else if (r < WI_SZ+WO_SZ+2*WX_SZ+WDT_SZ){
        int i = r - (WI_SZ+WO_SZ+2*WX_SZ);
        int rr = i >> 5, c = i & 31;
        v = (c < DTR) ? wdtf[(long)l*DI*DTR + rr*DTR + c] : 0.f;
    } else {
        int i = r - (WI_SZ+WO_SZ+2*WX_SZ+WDT_SZ);
        int rr = i >> 5, c = i & 31;
        v = (c < DTR) ? wdtb[(long)l*DI*DTR + rr*DTR + c] : 0.f;
    }
    out[(long)ly*WCVT_TOTAL + r] = f2us(v);
}

// ---------------- MFMA GEMM, bf16 A: C[M,N] = A[M,K] * W[N,K]^T -------------------
// MT = m-subtiles per wave (block covers MT*16 rows x 64 cols).
// modes: 0 out_proj -> res += v (N=DM); 1 in_proj split -> bf16 xi/zi;
//        2 patch epilogue -> res = v+aux; 3 dt softplus+bias(z) -> bf16;
//        4 xproj dual (f32 56 + bf16 32 pad0)
template<int MT>
__global__ __launch_bounds__(256) void gemm_mfma_kernel(
        const ushort_t* __restrict__ A, int lda, long strideA,
        const ushort_t* __restrict__ W, int ldw, long strideW,
        int K, int N,
        float* __restrict__ out0, long strideO0,
        ushort_t* __restrict__ outb0, ushort_t* __restrict__ outb1, long strideOb,
        int mode,
        const float* __restrict__ aux0, const float* __restrict__ aux1,
        const float* __restrict__ aux2)
{
    int z = blockIdx.z;
    A += (long)z * strideA;
    W += (long)z * strideW;
    if (out0)  out0  += (long)z * strideO0;
    if (outb0) outb0 += (long)z * strideOb;

    int tid  = threadIdx.x;
    int wave = tid >> 6, lane = tid & 63;
    int l15 = lane & 15, quad = lane >> 4;
    int m0 = blockIdx.y * (MT*16), n0 = blockIdx.x * 64;

    const ushort_t* wp  = W + (long)(n0 + wave*16 + l15)*ldw + quad*8;
    const ushort_t* ap0 = A + (long)(m0 + l15)*lda + quad*8;

    f32x4 acc[MT];
    #pragma unroll
    for (int mt = 0; mt < MT; mt++) acc[mt] = f32x4{0,0,0,0};

    for (int k0 = 0; k0 < K; k0 += 32){
        bf16x8 bfrag = *reinterpret_cast<const bf16x8*>(wp + k0);
        #pragma unroll
        for (int mt = 0; mt < MT; mt++){
            bf16x8 afrag = *reinterpret_cast<const bf16x8*>(ap0 + (long)mt*16*lda + k0);
            acc[mt] = __builtin_amdgcn_mfma_f32_16x16x32_bf16(afrag, bfrag, acc[mt], 0, 0, 0);
        }
    }

    int cn = n0 + wave*16 + l15;
    #pragma unroll
    for (int mt = 0; mt < MT; mt++){
        #pragma unroll
        for (int r = 0; r < 4; r++){
            int row = m0 + mt*16 + quad*4 + r;
            float v = acc[mt][r];
            if (mode == 0){
                out0[(long)row*N + cn] += v;
            } else if (mode == 1){
                if (cn < DI) outb0[(long)row*DI + cn] = f2us(v);
                else         outb1[(long)row*DI + cn - DI] = f2us(v);
            } else if (mode == 2){
                int tok = row % NTOK, t = (row/NTOK) % FRAMES;
                out0[(long)row*N + cn] = v + aux0[cn] + aux1[tok*DM+cn] + aux2[t*DM+cn];
            } else if (mode == 3){
                const float* bias = z ? aux1 : aux0;
                float xs = v + bias[cn];
                float sp = (xs > 20.f) ? xs : log1pf(__expf(xs));
                outb0[(long)row*N + cn] = f2us(sp);
            } else { // mode 4
                if (cn < 56) out0[(long)row*56 + cn] = v;
                if (cn < 32) outb0[(long)row*32 + cn] = f2us(cn < DTR ? v : 0.f);
            }
        }
    }
}

// ---------------- rmsnorm (read-only res), bf16 out ------------------------------
__global__ __launch_bounds__(128) void rmsnorm_kernel(
        const float* __restrict__ res,
        ushort_t* __restrict__ outb, const float* __restrict__ w)
{
    int r = blockIdx.x; int tid = threadIdx.x;
    const float* rr = res + (long)r*DM;
    float v[3]; float ss = 0.f;
    #pragma unroll
    for (int i = 0; i < 3; i++){
        int c = tid + i*128;
        float x = rr[c];
        v[i] = x; ss += x*x;
    }
    #pragma unroll
    for (int off = 32; off; off >>= 1) ss += __shfl_down(ss, off, 64);
    __shared__ float wsum[2];
    if ((tid & 63) == 0) wsum[tid >> 6] = ss;
    __syncthreads();
    float scale = rsqrtf((wsum[0] + wsum[1]) / (float)DM + EPS_);
    #pragma unroll
    for (int i = 0; i < 3; i++){
        int c = tid + i*128;
        outb[(long)r*DM + c] = f2us(v[i] * scale * w[c]);
    }
}

// ---------------- depthwise causal conv + silu -> bf16 ---------------------------
__global__ __launch_bounds__(256) void conv_kernel(
        const ushort_t* __restrict__ xi,
        const float* __restrict__ cw_f, const float* __restrict__ cb_f,
        const float* __restrict__ cw_b, const float* __restrict__ cb_b,
        ushort_t* __restrict__ xcb)
{
    int vidx = blockIdx.x*256 + threadIdx.x;
    if (vidx >= 2*NROWS*192) return;
    int dq = vidx % 192; int d4 = dq*4;
    int r2 = vidx / 192;
    int dir = r2 / NROWS;
    int rr  = r2 % NROWS;
    int b = rr / L_SEQ, p = rr % L_SEQ;
    const float* cw = dir ? cw_b : cw_f;
    const float* cb = dir ? cb_b : cb_f;
    float w[4][4];
    #pragma unroll
    for (int dd = 0; dd < 4; dd++){
        float4 wv = *(const float4*)(cw + (d4+dd)*KCONV);
        w[dd][0]=wv.x; w[dd][1]=wv.y; w[dd][2]=wv.z; w[dd][3]=wv.w;
    }
    float4 acc = *(const float4*)(cb + d4);
    #pragma unroll
    for (int j = 0; j < KCONV; j++){
        int pp = p - (KCONV-1) + j;
        if (pp >= 0){
            int phys = dir ? (L_SEQ-1-pp) : pp;
            ushort4 u = *(const ushort4*)(xi + ((long)b*L_SEQ + phys)*DI + d4);
            acc.x += w[0][j]*us2f(u.x);
            acc.y += w[1][j]*us2f(u.y);
            acc.z += w[2][j]*us2f(u.z);
            acc.w += w[3][j]*us2f(u.w);
        }
    }
    ushort4 ob;
    ob.x = f2us(acc.x/(1.f+__expf(-acc.x)));
    ob.y = f2us(acc.y/(1.f+__expf(-acc.y)));
    ob.z = f2us(acc.z/(1.f+__expf(-acc.z)));
    ob.w = f2us(acc.w/(1.f+__expf(-acc.w)));
    *(ushort4*)(xcb + (long)r2*DI + d4) = ob;
}

// ---------------- chunked selective scan: pass1 -----------------------------------
__global__ __launch_bounds__(256) void scan_pass1_kernel(
        const ushort_t* __restrict__ xcb, const ushort_t* __restrict__ dtb,
        const float* __restrict__ xdbl2,
        const float* __restrict__ Alog_f, const float* __restrict__ Alog_b,
        float* __restrict__ Pbuf, float* __restrict__ Sbuf)
{
    int dchunk = blockIdx.x;
    int chunk  = blockIdx.y;
    int z      = blockIdx.z;
    int b = z & 1, dir = z >> 1;
    int tid = threadIdx.x;
    int dl = tid >> 2, nq = tid & 3;
    int dbase = dchunk*DTILE;
    int d = dbase + dl;

    const ushort_t* xc = xcb + (long)dir*NROWS*DI;
    const ushort_t* dt = dtb + (long)dir*NROWS*DI;
    const float* xd = xdbl2 + (long)dir*NROWS*56;
    const float* Alog = dir ? Alog_b : Alog_f;

    float Av2[4];
    #pragma unroll
    for (int j = 0; j < 4; j++)
        Av2[j] = -__expf(Alog[d*DS + nq*4 + j]) * LOG2E;

    __shared__ float sdt[CLEN][DTILE], sxc[CLEN][DTILE], sB[CLEN][16];
    int c0 = chunk * CLEN;
    for (int e = tid; e < CLEN*16; e += 256){
        int s = e >> 4, q4 = (e & 15)*4;
        long row = (long)b*L_SEQ + c0 + s;
        ushort4 du = *(const ushort4*)(dt + row*DI + dbase + q4);
        ushort4 xu = *(const ushort4*)(xc + row*DI + dbase + q4);
        float4 df; df.x=us2f(du.x); df.y=us2f(du.y); df.z=us2f(du.z); df.w=us2f(du.w);
        float4 xf; xf.x=us2f(xu.x); xf.y=us2f(xu.y); xf.z=us2f(xu.z); xf.w=us2f(xu.w);
        *(float4*)&sdt[s][q4] = df;
        *(float4*)&sxc[s][q4] = xf;
    }
    for (int e = tid; e < CLEN*4; e += 256){
        int s = e >> 2, q4 = (e & 3)*4;
        long row = (long)b*L_SEQ + c0 + s;
        *(float4*)&sB[s][q4] = *(const float4*)(xd + row*56 + DTR + q4);
    }
    __syncthreads();

    float h0=0.f,h1=0.f,h2=0.f,h3=0.f, dts=0.f;
    for (int s = 0; s < CLEN; s++){
        float dtv = sdt[s][dl], xcv = sxc[s][dl];
        float4 Bv = *(float4*)&sB[s][nq*4];
        float tmp = dtv*xcv;
        dts += dtv;
        h0 = exp2f(dtv*Av2[0])*h0 + tmp*Bv.x;
        h1 = exp2f(dtv*Av2[1])*h1 + tmp*Bv.y;
        h2 = exp2f(dtv*Av2[2])*h2 + tmp*Bv.z;
        h3 = exp2f(dtv*Av2[3])*h3 + tmp*Bv.w;
    }
    long idx = (((long)z*NCHUNK + chunk)*DI + d)*DS + nq*4;
    float4 P; P.x=exp2f(Av2[0]*dts); P.y=exp2f(Av2[1]*dts);
    P.z=exp2f(Av2[2]*dts); P.w=exp2f(Av2[3]*dts);
    float4 S; S.x=h0; S.y=h1; S.z=h2; S.w=h3;
    *(float4*)(Pbuf + idx) = P;
    *(float4*)(Sbuf + idx) = S;
}

// ---------------- combine: grouped prefetch (8 chunks/group) ----------------------
__global__ __launch_bounds__(256) void scan_combine_kernel(
        const float* __restrict__ Pbuf, float* __restrict__ Sbuf)
{
    int gid = blockIdx.x*256 + threadIdx.x;
    if (gid >= 4*DI*DS/4) return;
    int dn4 = (gid % (DI*DS/4))*4;
    int z   = gid / (DI*DS/4);
    long idx = (long)z*NCHUNK*DI*DS + dn4;
    float4 hin = {0.f,0.f,0.f,0.f};
    for (int cg = 0; cg < NCHUNK; cg += 8){
        float4 P[8], S[8];
        #pragma unroll
        for (int j = 0; j < 8; j++){
            P[j] = *(const float4*)(Pbuf + idx + (long)j*DI*DS);
            S[j] = *(const float4*)(Sbuf + idx + (long)j*DI*DS);
        }
        #pragma unroll
        for (int j = 0; j < 8; j++){
            *(float4*)(Sbuf + idx + (long)j*DI*DS) = hin;
            hin.x = P[j].x*hin.x + S[j].x;
            hin.y = P[j].y*hin.y + S[j].y;
            hin.z = P[j].z*hin.z + S[j].z;
            hin.w = P[j].w*hin.w + S[j].w;
        }
        idx += (long)8*DI*DS;
    }
}

// ---------------- pass2: bf16 in, bf16 ys out ------------------------------------
__global__ __launch_bounds__(256) void scan_pass2_kernel(
        const ushort_t* __restrict__ xcb, const ushort_t* __restrict__ dtb,
        const float* __restrict__ xdbl2,
        const float* __restrict__ Alog_f, const float* __restrict__ Dp_f,
        const float* __restrict__ Alog_b, const float* __restrict__ Dp_b,
        const float* __restrict__ Hbuf,
        ushort_t* __restrict__ ys_f, ushort_t* __restrict__ ys_b)
{
    int dchunk = blockIdx.x;
    int chunk  = blockIdx.y;
    int z      = blockIdx.z;
    int b = z & 1, dir = z >> 1;
    int tid = threadIdx.x;
    int dl = tid >> 2, nq = tid & 3;
    int dbase = dchunk*DTILE;
    int d = dbase + dl;

    const ushort_t* xc = xcb + (long)dir*NROWS*DI;
    const ushort_t* dt = dtb + (long)dir*NROWS*DI;
    const float* xd = xdbl2 + (long)dir*NROWS*56;
    const float* Alog = dir ? Alog_b : Alog_f;
    const float* Dpp  = dir ? Dp_b   : Dp_f;
    ushort_t* ys = dir ? ys_b : ys_f;

    float Av2[4];
    #pragma unroll
    for (int j = 0; j < 4; j++)
        Av2[j] = -__expf(Alog[d*DS + nq*4 + j]) * LOG2E;
    float Dval = Dpp[d];

    __shared__ float sdt[CLEN][DTILE], sxc[CLEN][DTILE], sB[CLEN][16], sC[CLEN][16];
    int c0 = chunk * CLEN;
    for (int e = tid; e < CLEN*16; e += 256){
        int s = e >> 4, q4 = (e & 15)*4;
        long row = (long)b*L_SEQ + c0 + s;
        ushort4 du = *(const ushort4*)(dt + row*DI + dbase + q4);
        ushort4 xu = *(const ushort4*)(xc + row*DI + dbase + q4);
        float4 df; df.x=us2f(du.x); df.y=us2f(du.y); df.z=us2f(du.z); df.w=us2f(du.w);
        float4 xf; xf.x=us2f(xu.x); xf.y=us2f(xu.y); xf.z=us2f(xu.z); xf.w=us2f(xu.w);
        *(float4*)&sdt[s][q4] = df;
        *(float4*)&sxc[s][q4] = xf;
    }
    for (int e = tid; e < CLEN*4; e += 256){
        int s = e >> 2, q4 = (e & 3)*4;
        long row = (long)b*L_SEQ + c0 + s;
        *(float4*)&sB[s][q4] = *(const float4*)(xd + row*56 + DTR + q4);
        *(float4*)&sC[s][q4] = *(const float4*)(xd + row*56 + DTR + DS + q4);
    }
    __syncthreads();

    long idx = (((long)z*NCHUNK + chunk)*DI + d)*DS + nq*4;
    float4 H = *(const float4*)(Hbuf + idx);
    float h0=H.x, h1=H.y, h2=H.z, h3=H.w;

    for (int s = 0; s < CLEN; s++){
        float dtv = sdt[s][dl], xcv = sxc[s][dl];
        float4 Bv = *(float4*)&sB[s][nq*4];
        float4 Cv = *(float4*)&sC[s][nq*4];
        float tmp = dtv*xcv;
        h0 = exp2f(dtv*Av2[0])*h0 + tmp*Bv.x;
        h1 = exp2f(dtv*Av2[1])*h1 + tmp*Bv.y;
        h2 = exp2f(dtv*Av2[2])*h2 + tmp*Bv.z;
        h3 = exp2f(dtv*Av2[3])*h3 + tmp*Bv.w;
        float c = h0*Cv.x + h1*Cv.y + h2*Cv.z + h3*Cv.w;
        c += __shfl_xor(c, 1);
        c += __shfl_xor(c, 2);
        if (nq == 0){
            int p = c0 + s;
            int phys = dir ? (L_SEQ-1-p) : p;
            ys[((long)b*L_SEQ + phys)*DI + d] = f2us(c + Dval*xcv);
        }
    }
}

// ---------------- ys gate: (ysf+ysb)*silu(z) -> bf16 -----------------------------
__global__ __launch_bounds__(256) void ys_gate_kernel(
        const ushort_t* __restrict__ ysf, const ushort_t* __restrict__ ysb,
        const ushort_t* __restrict__ zi, ushort_t* __restrict__ out)
{
    int i4 = (blockIdx.x*256 + threadIdx.x)*4;
    if (i4 >= NROWS*DI) return;
    ushort4 a = *(const ushort4*)(ysf + i4);
    ushort4 bb = *(const ushort4*)(ysb + i4);
    ushort4 u = *(const ushort4*)(zi + i4);
    ushort4 r;
    {
        float zv = us2f(u.x); float g = zv/(1.f+__expf(-zv));
        r.x = f2us((us2f(a.x)+us2f(bb.x))*g);
    }{
        float zv = us2f(u.y); float g = zv/(1.f+__expf(-zv));
        r.y = f2us((us2f(a.y)+us2f(bb.y))*g);
    }{
        float zv = us2f(u.z); float g = zv/(1.f+__expf(-zv));
        r.z = f2us((us2f(a.z)+us2f(bb.z))*g);
    }{
        float zv = us2f(u.w); float g = zv/(1.f+__expf(-zv));
        r.w = f2us((us2f(a.w)+us2f(bb.w))*g);
    }
    *(ushort4*)(out + i4) = r;
}

// ---------------- final rmsnorm (read-only res) ----------------------------------
__global__ __launch_bounds__(128) void rmsnorm_final_kernel(
        const float* __restrict__ res,
        const float* __restrict__ w, float* __restrict__ out)
{
    int r = blockIdx.x; int tid = threadIdx.x;
    const float* rr = res + (long)r*DM;
    float v[3]; float ss = 0.f;
    #pragma unroll
    for (int i = 0; i < 3; i++){
        int c = tid + i*128;
        float x = rr[c];
        v[i] = x; ss += x*x;
    }
    #pragma unroll
    for (int off = 32; off; off >>= 1) ss += __shfl_down(ss, off, 64);
    __shared__ float wsum[2];
    if ((tid & 63) == 0) wsum[tid >> 6] = ss;
    __syncthreads();
    float scale = rsqrtf((wsum[0] + wsum[1]) / (float)DM + EPS_);
    #pragma unroll
    for (int i = 0; i < 3; i++){
        int c = tid + i*128;
        out[(long)r*DM + c] = v[i] * scale * w[c];
    }
}

extern "C" void kernel_launch(void* const* d_in, const int* in_sizes, int n_in,
                              void* d_out, int out_size, void* d_ws, size_t ws_size,
                              hipStream_t stream)
{
    const float* x         = (const float*)d_in[0];
    const float* patch_w   = (const float*)d_in[1];
    const float* patch_b   = (const float*)d_in[2];
    const float* pos_embed = (const float*)d_in[3];
    const float* temp_pos  = (const float*)d_in[4];
    const float* in_proj   = (const float*)d_in[5];
    const float* conv_w    = (const float*)d_in[6];
    const float* conv_b    = (const float*)d_in[7];
    const float* xproj_w   = (const float*)d_in[8];
    const float* dt_w      = (const float*)d_in[9];
    const float* dt_b      = (const float*)d_in[10];
    const float* A_log     = (const float*)d_in[11];
    const float* Dp        = (const float*)d_in[12];
    const float* conv_w_b  = (const float*)d_in[13];
    const float* conv_b_b  = (const float*)d_in[14];
    const float* xproj_w_b = (const float*)d_in[15];
    const float* dt_w_b    = (const float*)d_in[16];
    const float* dt_b_b    = (const float*)d_in[17];
    const float* A_log_b   = (const float*)d_in[18];
    const float* Dp_b      = (const float*)d_in[19];
    const float* out_proj  = (const float*)d_in[20];
    const float* norm_w    = (const float*)d_in[21];
    const float* norm_f    = (const float*)d_in[22];

    float* ws = (float*)d_ws;
    size_t off = 0;
    float* residual = ws + off; off += (size_t)NROWS*DM;           // 1,204,224
    float* hnormreg = ws + off; off += (size_t)NROWS*DM/2;         // bf16 hnorm; Pbuf head
    float* xireg    = ws + off; off += (size_t)NROWS*DI/2;         // bf16 xi; Pbuf tail
    float* zireg    = ws + off; off += (size_t)NROWS*DI/2;         // bf16 zi; ys_bf alias
    float* xc2bfreg = ws + off; off += (size_t)NROWS*DI;           // bf16 xc, 2 dirs
    float* xdbl2    = ws + off; off += (size_t)2*NROWS*56;
    float* xdblbf_f = ws + off; off += (size_t)2*NROWS*32/2;
    float* dt2bfreg = ws + off; off += (size_t)NROWS*DI;           // bf16 dt, 2 dirs; patches alias
    float* ysfbfreg = ws + off; off += (size_t)NROWS*DI/2;
    float* ysbbfreg = ws + off; off += (size_t)NROWS*DI/2;
    float* Sbuf     = ws + off; off += (size_t)4*NCHUNK*DI*DS;     // 1,572,864
    float* wpbf_f   = ws + off; off += (size_t)(DM*DI+1)/2;
    size_t fixed_floats = off;
    const size_t perW = (size_t)(WCVT_TOTAL+1)/2;
    // weight group size: 24 if ws allows (~103.5 MB), else 8 (~70.8 MB, proven safe)
    int G = (ws_size/4 >= fixed_floats + 24*perW) ? 24
          : (ws_size/4 >= fixed_floats + 8*perW)  ? 8 : 1;
    float* wbf_f = ws + off; off += G*perW;

    ushort_t* hnorm_bf   = (ushort_t*)hnormreg;
    ushort_t* xi_bf      = (ushort_t*)xireg;
    ushort_t* zi_bf      = (ushort_t*)zireg;
    ushort_t* ys_bf      = (ushort_t*)zireg;   // gate reads zi[i], writes out[i]: safe
    ushort_t* xc2_bf     = (ushort_t*)xc2bfreg;
    ushort_t* xdbl_bf    = (ushort_t*)xdblbf_f;
    ushort_t* dt2_bf     = (ushort_t*)dt2bfreg;
    ushort_t* ysf_bf     = (ushort_t*)ysfbfreg;
    ushort_t* ysb_bf     = (ushort_t*)ysbbfreg;
    ushort_t* patches_bf = (ushort_t*)dt2bfreg;  // dead before dt GEMM of layer 0
    ushort_t* wbuf       = (ushort_t*)wbf_f;
    ushort_t* wp_bf      = (ushort_t*)wpbf_f;
    float* Pbuf = hnormreg;   // 1,572,864 floats over hnorm+xi; both dead by pass1

    patchify_kernel<<<(NROWS*768+255)/256, 256, 0, stream>>>(x, patches_bf);
    convert_kernel<<<(DM*DI+255)/256, 256, 0, stream>>>(patch_w, wp_bf, DM*DI);
    // patch embed -> residual (mode 2 stores v+aux)
    gemm_mfma_kernel<4><<<dim3(DM/64, NROWS/64, 1), 256, 0, stream>>>(
        patches_bf, DI, 0, wp_bf, DI, 0, DI, DM,
        residual, 0, nullptr, nullptr, 0, 2, patch_b, pos_embed, temp_pos);

    for (int l = 0; l < DEPTH; l++){
        if (l % G == 0){
            int cnt = (DEPTH - l < G) ? DEPTH - l : G;
            long total = (long)cnt*WCVT_TOTAL;
            convert_group_kernel<<<(int)((total+255)/256), 256, 0, stream>>>(
                in_proj, out_proj, xproj_w, xproj_w_b, dt_w, dt_w_b,
                wbuf, l, cnt);
        }
        ushort_t* wl = wbuf + (size_t)(l % G)*WCVT_TOTAL;
        ushort_t* wi_bf  = wl;
        ushort_t* wo_bf  = wl + WI_SZ;
        ushort_t* wx_bf  = wl + WI_SZ + WO_SZ;
        ushort_t* wdt_bf = wl + WI_SZ + WO_SZ + 2*WX_SZ;

        rmsnorm_kernel<<<NROWS, 128, 0, stream>>>(residual, hnorm_bf,
                                                  norm_w + (size_t)l*DM);
        // in_proj -> xi_bf, zi_bf
        gemm_mfma_kernel<4><<<dim3(2*DI/64, NROWS/64, 1), 256, 0, stream>>>(
            hnorm_bf, DM, 0, wi_bf, DM, 0, DM, 2*DI,
            nullptr, 0, xi_bf, zi_bf, 0, 1, nullptr, nullptr, nullptr);

        conv_kernel<<<(2*NROWS*192+255)/256, 256, 0, stream>>>(
            xi_bf, conv_w + (size_t)l*DI*KCONV, conv_b + (size_t)l*DI,
            conv_w_b + (size_t)l*DI*KCONV, conv_b_b + (size_t)l*DI, xc2_bf);

        // xproj fwd+bwd (MT=1: 16-row tiles, 392 blocks)
        gemm_mfma_kernel<1><<<dim3(1, NROWS/16, 2), 256, 0, stream>>>(
            xc2_bf, DI, (long)NROWS*DI, wx_bf, DI, WX_SZ, DI, 64,
            xdbl2, (long)NROWS*56, xdbl_bf, nullptr, (long)NROWS*32, 4,
            nullptr, nullptr, nullptr);

        // dt fwd+bwd
        gemm_mfma_kernel<4><<<dim3(DI/64, NROWS/64, 2), 256, 0, stream>>>(
            xdbl_bf, 32, (long)NROWS*32, wdt_bf, 32, WDT_SZ, 32, DI,
            nullptr, 0, dt2_bf, nullptr, (long)NROWS*DI, 3,
            dt_b + (size_t)l*DI, dt_b_b + (size_t)l*DI, nullptr);

        scan_pass1_kernel<<<dim3(NDC, NCHUNK, 4), 256, 0, stream>>>(
            xc2_bf, dt2_bf, xdbl2, A_log + (size_t)l*DI*DS, A_log_b + (size_t)l*DI*DS,
            Pbuf, Sbuf);
        scan_combine_kernel<<<(4*DI*DS/4+255)/256, 256, 0, stream>>>(Pbuf, Sbuf);
        scan_pass2_kernel<<<dim3(NDC, NCHUNK, 4), 256, 0, stream>>>(
            xc2_bf, dt2_bf, xdbl2,
            A_log + (size_t)l*DI*DS, Dp + (size_t)l*DI,
            A_log_b + (size_t)l*DI*DS, Dp_b + (size_t)l*DI,
            Sbuf, ysf_bf, ysb_bf);

        ys_gate_kernel<<<(NROWS*DI/4+255)/256, 256, 0, stream>>>(ysf_bf, ysb_bf, zi_bf, ys_bf);

        // out_proj: ys_bf x wo^T -> residual += (mode 0)
        gemm_mfma_kernel<4><<<dim3(DM/64, NROWS/64, 1), 256, 0, stream>>>(
            ys_bf, DI, 0, wo_bf, DI, 0, DI, DM,
            residual, 0, nullptr, nullptr, 0, 0, nullptr, nullptr, nullptr);
    }

    rmsnorm_final_kernel<<<NROWS, 128, 0, stream>>>(residual, norm_f, (float*)d_out);
}

// Round 9
// 4228.595 us; speedup vs baseline: 1.8977x; 1.2232x over previous
//
#include <hip/hip_runtime.h>
#include <hip/hip_bf16.h>

typedef unsigned short ushort_t;
typedef short bf16x8 __attribute__((ext_vector_type(8)));
typedef unsigned short us16x8 __attribute__((ext_vector_type(8)));
typedef float f32x4  __attribute__((ext_vector_type(4)));

#define BATCH   2
#define FRAMES  8
#define GRID_   14
#define NTOK    196
#define PS      16
#define IMG     224
#define L_SEQ   1568
#define DM      384
#define DI      768
#define DTR     24
#define DS      16
#define DEPTH   24
#define KCONV   4
#define NROWS   (BATCH*L_SEQ)   // 3136
#define EPS_    1e-5f
#define NCHUNK  32
#define CLEN    49              // 32*49 = 1568
#define DTILE   64
#define NDC     (DI/DTILE)      // 12
#define LOG2E   1.4426950408889634f

__device__ __forceinline__ ushort_t f2us(float f){
    __hip_bfloat16 h = __float2bfloat16(f);
    return *reinterpret_cast<ushort_t*>(&h);
}
__device__ __forceinline__ float us2f(ushort_t u){
    return __uint_as_float(((unsigned int)u) << 16);
}

// ---------------- patchify ------------------------------------------------------
__global__ __launch_bounds__(256) void patchify_kernel(const float* __restrict__ x,
                                                       ushort_t* __restrict__ patches){
    int idx = blockIdx.x*256 + threadIdx.x;
    if (idx >= NROWS*768) return;
    int k   = idx % 768;
    int r   = idx / 768;
    int tok = r % NTOK;
    int bt  = r / NTOK;
    int t = bt % FRAMES, b = bt / FRAMES;
    int gy = tok / GRID_, gx = tok % GRID_;
    int c = k / 256; int rem = k % 256; int py = rem/16, px = rem%16;
    long xo = (((long)(b*3 + c)*FRAMES + t)*IMG + (gy*PS+py))*IMG + (gx*PS+px);
    patches[idx] = f2us(x[xo]);
}

__global__ __launch_bounds__(256) void convert_kernel(const float* __restrict__ in,
                                                      ushort_t* __restrict__ out, int n){
    int i = blockIdx.x*256 + threadIdx.x;
    if (i < n) out[i] = f2us(in[i]);
}

// ---------------- grouped weight conversion --------------------------------------
#define WI_SZ  (2*DI*DM)
#define WO_SZ  (DM*DI)
#define WX_SZ  (56*DI)
#define WDT_SZ (DI*32)
#define WCVT_TOTAL (WI_SZ + WO_SZ + 2*WX_SZ + 2*WDT_SZ)   // 1,019,904

__global__ __launch_bounds__(256) void convert_group_kernel(
        const float* __restrict__ wi, const float* __restrict__ wo,
        const float* __restrict__ wxf, const float* __restrict__ wxb,
        const float* __restrict__ wdtf, const float* __restrict__ wdtb,
        ushort_t* __restrict__ out, int l0, int count)
{
    long gid = (long)blockIdx.x*256 + threadIdx.x;
    if (gid >= (long)count*WCVT_TOTAL) return;
    int ly = (int)(gid / WCVT_TOTAL);
    int r  = (int)(gid % WCVT_TOTAL);
    int l  = l0 + ly;
    float v;
    if (r < WI_SZ)                       v = wi[(long)l*WI_SZ + r];
    else if (r < WI_SZ+WO_SZ)            v = wo[(long)l*WO_SZ + r - WI_SZ];
    else if (r < WI_SZ+WO_SZ+WX_SZ)      v = wxf[(long)l*WX_SZ + r - WI_SZ - WO_SZ];
    else if (r < WI_SZ+WO_SZ+2*WX_SZ)    v = wxb[(long)l*WX_SZ + r - WI_SZ - WO_SZ - WX_SZ];
    else if (r < WI_SZ+WO_SZ+2*WX_SZ+WDT_SZ){
        int i = r - (WI_SZ+WO_SZ+2*WX_SZ);
        int rr = i >> 5, c = i & 31;
        v = (c < DTR) ? wdtf[(long)l*DI*DTR + rr*DTR + c] : 0.f;
    } else {
        int i = r - (WI_SZ+WO_SZ+2*WX_SZ+WDT_SZ);
        int rr = i >> 5, c = i & 31;
        v = (c < DTR) ? wdtb[(long)l*DI*DTR + rr*DTR + c] : 0.f;
    }
    out[(long)ly*WCVT_TOTAL + r] = f2us(v);
}

// ---------------- MFMA GEMM: C[M,N] = A[M,K] * W[N,K]^T --------------------------
// STAGE=1: A-tile staged through double-buffered LDS (shared by 4 waves).
// modes: 0 out_proj -> res +=; 1 in_proj split -> bf16 xi/zi; 2 patch -> res=v+aux;
//        3 dt softplus+bias(z) -> bf16; 4 xproj dual (f32 56 + bf16 32 pad0)
template<int MT, int STAGE>
__global__ __launch_bounds__(256) void gemm_mfma_kernel(
        const ushort_t* __restrict__ A, int lda, long strideA,
        const ushort_t* __restrict__ W, int ldw, long strideW,
        int K, int N,
        float* __restrict__ out0, long strideO0,
        ushort_t* __restrict__ outb0, ushort_t* __restrict__ outb1, long strideOb,
        int mode,
        const float* __restrict__ aux0, const float* __restrict__ aux1,
        const float* __restrict__ aux2)
{
    int z = blockIdx.z;
    A += (long)z * strideA;
    W += (long)z * strideW;
    if (out0)  out0  += (long)z * strideO0;
    if (outb0) outb0 += (long)z * strideOb;

    int tid  = threadIdx.x;
    int wave = tid >> 6, lane = tid & 63;
    int l15 = lane & 15, quad = lane >> 4;
    int m0 = blockIdx.y * (MT*16), n0 = blockIdx.x * 64;

    const ushort_t* wp = W + (long)(n0 + wave*16 + l15)*ldw + quad*8;

    f32x4 acc[MT];
    #pragma unroll
    for (int mt = 0; mt < MT; mt++) acc[mt] = f32x4{0,0,0,0};

    if constexpr (STAGE){
        __shared__ alignas(16) ushort_t As[2][MT*16][40];
        bool act = (tid < MT*64);
        int srow = tid >> 2, skq = tid & 3;
        const ushort_t* ag = A + (long)(m0 + srow)*lda + skq*8;
        us16x8 av = {};
        if (act) av = *(const us16x8*)ag;
        int nIter = K >> 5;
        for (int it = 0; it < nIter; it++){
            if (act) *(us16x8*)&As[it&1][srow][skq*8] = av;
            if (act && it+1 < nIter) av = *(const us16x8*)(ag + (long)(it+1)*32);
            __syncthreads();
            bf16x8 bfrag = *reinterpret_cast<const bf16x8*>(wp + it*32);
            #pragma unroll
            for (int mt = 0; mt < MT; mt++){
                bf16x8 afrag = *reinterpret_cast<const bf16x8*>(&As[it&1][mt*16+l15][quad*8]);
                acc[mt] = __builtin_amdgcn_mfma_f32_16x16x32_bf16(afrag, bfrag, acc[mt], 0, 0, 0);
            }
        }
    } else {
        const ushort_t* ap0 = A + (long)(m0 + l15)*lda + quad*8;
        for (int k0 = 0; k0 < K; k0 += 32){
            bf16x8 bfrag = *reinterpret_cast<const bf16x8*>(wp + k0);
            #pragma unroll
            for (int mt = 0; mt < MT; mt++){
                bf16x8 afrag = *reinterpret_cast<const bf16x8*>(ap0 + (long)mt*16*lda + k0);
                acc[mt] = __builtin_amdgcn_mfma_f32_16x16x32_bf16(afrag, bfrag, acc[mt], 0, 0, 0);
            }
        }
    }

    int cn = n0 + wave*16 + l15;
    #pragma unroll
    for (int mt = 0; mt < MT; mt++){
        #pragma unroll
        for (int r = 0; r < 4; r++){
            int row = m0 + mt*16 + quad*4 + r;
            float v = acc[mt][r];
            if (mode == 0){
                out0[(long)row*N + cn] += v;
            } else if (mode == 1){
                if (cn < DI) outb0[(long)row*DI + cn] = f2us(v);
                else         outb1[(long)row*DI + cn - DI] = f2us(v);
            } else if (mode == 2){
                int tok = row % NTOK, t = (row/NTOK) % FRAMES;
                out0[(long)row*N + cn] = v + aux0[cn] + aux1[tok*DM+cn] + aux2[t*DM+cn];
            } else if (mode == 3){
                const float* bias = z ? aux1 : aux0;
                float xs = v + bias[cn];
                float sp = (xs > 20.f) ? xs : log1pf(__expf(xs));
                outb0[(long)row*N + cn] = f2us(sp);
            } else { // mode 4
                if (cn < 56) out0[(long)row*56 + cn] = v;
                if (cn < 32) outb0[(long)row*32 + cn] = f2us(cn < DTR ? v : 0.f);
            }
        }
    }
}

// ---------------- rmsnorm (read-only res), bf16 out ------------------------------
__global__ __launch_bounds__(128) void rmsnorm_kernel(
        const float* __restrict__ res,
        ushort_t* __restrict__ outb, const float* __restrict__ w)
{
    int r = blockIdx.x; int tid = threadIdx.x;
    const float* rr = res + (long)r*DM;
    float v[3]; float ss = 0.f;
    #pragma unroll
    for (int i = 0; i < 3; i++){
        int c = tid + i*128;
        float x = rr[c];
        v[i] = x; ss += x*x;
    }
    #pragma unroll
    for (int off = 32; off; off >>= 1) ss += __shfl_down(ss, off, 64);
    __shared__ float wsum[2];
    if ((tid & 63) == 0) wsum[tid >> 6] = ss;
    __syncthreads();
    float scale = rsqrtf((wsum[0] + wsum[1]) / (float)DM + EPS_);
    #pragma unroll
    for (int i = 0; i < 3; i++){
        int c = tid + i*128;
        outb[(long)r*DM + c] = f2us(v[i] * scale * w[c]);
    }
}

// ---------------- depthwise causal conv + silu -> bf16 ---------------------------
__global__ __launch_bounds__(256) void conv_kernel(
        const ushort_t* __restrict__ xi,
        const float* __restrict__ cw_f, const float* __restrict__ cb_f,
        const float* __restrict__ cw_b, const float* __restrict__ cb_b,
        ushort_t* __restrict__ xcb)
{
    int vidx = blockIdx.x*256 + threadIdx.x;
    if (vidx >= 2*NROWS*192) return;
    int dq = vidx % 192; int d4 = dq*4;
    int r2 = vidx / 192;
    int dir = r2 / NROWS;
    int rr  = r2 % NROWS;
    int b = rr / L_SEQ, p = rr % L_SEQ;
    const float* cw = dir ? cw_b : cw_f;
    const float* cb = dir ? cb_b : cb_f;
    float w[4][4];
    #pragma unroll
    for (int dd = 0; dd < 4; dd++){
        float4 wv = *(const float4*)(cw + (d4+dd)*KCONV);
        w[dd][0]=wv.x; w[dd][1]=wv.y; w[dd][2]=wv.z; w[dd][3]=wv.w;
    }
    float4 acc = *(const float4*)(cb + d4);
    #pragma unroll
    for (int j = 0; j < KCONV; j++){
        int pp = p - (KCONV-1) + j;
        if (pp >= 0){
            int phys = dir ? (L_SEQ-1-pp) : pp;
            ushort4 u = *(const ushort4*)(xi + ((long)b*L_SEQ + phys)*DI + d4);
            acc.x += w[0][j]*us2f(u.x);
            acc.y += w[1][j]*us2f(u.y);
            acc.z += w[2][j]*us2f(u.z);
            acc.w += w[3][j]*us2f(u.w);
        }
    }
    ushort4 ob;
    ob.x = f2us(acc.x/(1.f+__expf(-acc.x)));
    ob.y = f2us(acc.y/(1.f+__expf(-acc.y)));
    ob.z = f2us(acc.z/(1.f+__expf(-acc.z)));
    ob.w = f2us(acc.w/(1.f+__expf(-acc.w)));
    *(ushort4*)(xcb + (long)r2*DI + d4) = ob;
}

// ---------------- chunked selective scan: pass1 (bf16 LDS) ------------------------
__global__ __launch_bounds__(256) void scan_pass1_kernel(
        const ushort_t* __restrict__ xcb, const ushort_t* __restrict__ dtb,
        const float* __restrict__ xdbl2,
        const float* __restrict__ Alog_f, const float* __restrict__ Alog_b,
        float* __restrict__ Pbuf, float* __restrict__ Sbuf)
{
    int dchunk = blockIdx.x;
    int chunk  = blockIdx.y;
    int z      = blockIdx.z;
    int b = z & 1, dir = z >> 1;
    int tid = threadIdx.x;
    int dl = tid >> 2, nq = tid & 3;
    int dbase = dchunk*DTILE;
    int d = dbase + dl;

    const ushort_t* xc = xcb + (long)dir*NROWS*DI;
    const ushort_t* dt = dtb + (long)dir*NROWS*DI;
    const float* xd = xdbl2 + (long)dir*NROWS*56;
    const float* Alog = dir ? Alog_b : Alog_f;

    float Av2[4];
    #pragma unroll
    for (int j = 0; j < 4; j++)
        Av2[j] = -__expf(Alog[d*DS + nq*4 + j]) * LOG2E;

    __shared__ ushort_t sdt[CLEN][DTILE], sxc[CLEN][DTILE];
    __shared__ float sB[CLEN][16];
    int c0 = chunk * CLEN;
    for (int e = tid; e < CLEN*16; e += 256){
        int s = e >> 4, q4 = (e & 15)*4;
        long row = (long)b*L_SEQ + c0 + s;
        *(ushort4*)&sdt[s][q4] = *(const ushort4*)(dt + row*DI + dbase + q4);
        *(ushort4*)&sxc[s][q4] = *(const ushort4*)(xc + row*DI + dbase + q4);
    }
    for (int e = tid; e < CLEN*4; e += 256){
        int s = e >> 2, q4 = (e & 3)*4;
        long row = (long)b*L_SEQ + c0 + s;
        *(float4*)&sB[s][q4] = *(const float4*)(xd + row*56 + DTR + q4);
    }
    __syncthreads();

    float h0=0.f,h1=0.f,h2=0.f,h3=0.f, dts=0.f;
    for (int s = 0; s < CLEN; s++){
        float dtv = us2f(sdt[s][dl]), xcv = us2f(sxc[s][dl]);
        float4 Bv = *(float4*)&sB[s][nq*4];
        float tmp = dtv*xcv;
        dts += dtv;
        h0 = exp2f(dtv*Av2[0])*h0 + tmp*Bv.x;
        h1 = exp2f(dtv*Av2[1])*h1 + tmp*Bv.y;
        h2 = exp2f(dtv*Av2[2])*h2 + tmp*Bv.z;
        h3 = exp2f(dtv*Av2[3])*h3 + tmp*Bv.w;
    }
    long idx = (((long)z*NCHUNK + chunk)*DI + d)*DS + nq*4;
    float4 P; P.x=exp2f(Av2[0]*dts); P.y=exp2f(Av2[1]*dts);
    P.z=exp2f(Av2[2]*dts); P.w=exp2f(Av2[3]*dts);
    float4 S; S.x=h0; S.y=h1; S.z=h2; S.w=h3;
    *(float4*)(Pbuf + idx) = P;
    *(float4*)(Sbuf + idx) = S;
}

// ---------------- combine: grouped prefetch ---------------------------------------
__global__ __launch_bounds__(256) void scan_combine_kernel(
        const float* __restrict__ Pbuf, float* __restrict__ Sbuf)
{
    int gid = blockIdx.x*256 + threadIdx.x;
    if (gid >= 4*DI*DS/4) return;
    int dn4 = (gid % (DI*DS/4))*4;
    int z   = gid / (DI*DS/4);
    long idx = (long)z*NCHUNK*DI*DS + dn4;
    float4 hin = {0.f,0.f,0.f,0.f};
    for (int cg = 0; cg < NCHUNK; cg += 8){
        float4 P[8], S[8];
        #pragma unroll
        for (int j = 0; j < 8; j++){
            P[j] = *(const float4*)(Pbuf + idx + (long)j*DI*DS);
            S[j] = *(const float4*)(Sbuf + idx + (long)j*DI*DS);
        }
        #pragma unroll
        for (int j = 0; j < 8; j++){
            *(float4*)(Sbuf + idx + (long)j*DI*DS) = hin;
            hin.x = P[j].x*hin.x + S[j].x;
            hin.y = P[j].y*hin.y + S[j].y;
            hin.z = P[j].z*hin.z + S[j].z;
            hin.w = P[j].w*hin.w + S[j].w;
        }
        idx += (long)8*DI*DS;
    }
}

// ---------------- pass2: bf16 LDS, coalesced ys epilogue --------------------------
__global__ __launch_bounds__(256) void scan_pass2_kernel(
        const ushort_t* __restrict__ xcb, const ushort_t* __restrict__ dtb,
        const float* __restrict__ xdbl2,
        const float* __restrict__ Alog_f, const float* __restrict__ Dp_f,
        const float* __restrict__ Alog_b, const float* __restrict__ Dp_b,
        const float* __restrict__ Hbuf,
        ushort_t* __restrict__ ys_f, ushort_t* __restrict__ ys_b)
{
    int dchunk = blockIdx.x;
    int chunk  = blockIdx.y;
    int z      = blockIdx.z;
    int b = z & 1, dir = z >> 1;
    int tid = threadIdx.x;
    int dl = tid >> 2, nq = tid & 3;
    int dbase = dchunk*DTILE;
    int d = dbase + dl;

    const ushort_t* xc = xcb + (long)dir*NROWS*DI;
    const ushort_t* dt = dtb + (long)dir*NROWS*DI;
    const float* xd = xdbl2 + (long)dir*NROWS*56;
    const float* Alog = dir ? Alog_b : Alog_f;
    const float* Dpp  = dir ? Dp_b   : Dp_f;
    ushort_t* ys = dir ? ys_b : ys_f;

    float Av2[4];
    #pragma unroll
    for (int j = 0; j < 4; j++)
        Av2[j] = -__expf(Alog[d*DS + nq*4 + j]) * LOG2E;
    float Dval = Dpp[d];

    __shared__ ushort_t sdt[CLEN][DTILE], sxc[CLEN][DTILE], sy[CLEN][DTILE];
    __shared__ float sB[CLEN][16], sC[CLEN][16];
    int c0 = chunk * CLEN;
    for (int e = tid; e < CLEN*16; e += 256){
        int s = e >> 4, q4 = (e & 15)*4;
        long row = (long)b*L_SEQ + c0 + s;
        *(ushort4*)&sdt[s][q4] = *(const ushort4*)(dt + row*DI + dbase + q4);
        *(ushort4*)&sxc[s][q4] = *(const ushort4*)(xc + row*DI + dbase + q4);
    }
    for (int e = tid; e < CLEN*4; e += 256){
        int s = e >> 2, q4 = (e & 3)*4;
        long row = (long)b*L_SEQ + c0 + s;
        *(float4*)&sB[s][q4] = *(const float4*)(xd + row*56 + DTR + q4);
        *(float4*)&sC[s][q4] = *(const float4*)(xd + row*56 + DTR + DS + q4);
    }
    __syncthreads();

    long idx = (((long)z*NCHUNK + chunk)*DI + d)*DS + nq*4;
    float4 H = *(const float4*)(Hbuf + idx);
    float h0=H.x, h1=H.y, h2=H.z, h3=H.w;

    for (int s = 0; s < CLEN; s++){
        float dtv = us2f(sdt[s][dl]), xcv = us2f(sxc[s][dl]);
        float4 Bv = *(float4*)&sB[s][nq*4];
        float4 Cv = *(float4*)&sC[s][nq*4];
        float tmp = dtv*xcv;
        h0 = exp2f(dtv*Av2[0])*h0 + tmp*Bv.x;
        h1 = exp2f(dtv*Av2[1])*h1 + tmp*Bv.y;
        h2 = exp2f(dtv*Av2[2])*h2 + tmp*Bv.z;
        h3 = exp2f(dtv*Av2[3])*h3 + tmp*Bv.w;
        float c = h0*Cv.x + h1*Cv.y + h2*Cv.z + h3*Cv.w;
        c += __shfl_xor(c, 1);
        c += __shfl_xor(c, 2);
        if (nq == 0) sy[s][dl] = f2us(c + Dval*xcv);
    }
    __syncthreads();

    for (int e = tid; e < CLEN*16; e += 256){
        int s = e >> 4, q4 = (e & 15)*4;
        int p = c0 + s;
        int phys = dir ? (L_SEQ-1-p) : p;
        *(ushort4*)(ys + ((long)b*L_SEQ + phys)*DI + dbase + q4) = *(ushort4*)&sy[s][q4];
    }
}

// ---------------- ys gate: (ysf+ysb)*silu(z) -> bf16 -----------------------------
__global__ __launch_bounds__(256) void ys_gate_kernel(
        const ushort_t* __restrict__ ysf, const ushort_t* __restrict__ ysb,
        const ushort_t* __restrict__ zi, ushort_t* __restrict__ out)
{
    int i4 = (blockIdx.x*256 + threadIdx.x)*4;
    if (i4 >= NROWS*DI) return;
    ushort4 a = *(const ushort4*)(ysf + i4);
    ushort4 bb = *(const ushort4*)(ysb + i4);
    ushort4 u = *(const ushort4*)(zi + i4);
    ushort4 r;
    {
        float zv = us2f(u.x); float g = zv/(1.f+__expf(-zv));
        r.x = f2us((us2f(a.x)+us2f(bb.x))*g);
    }{
        float zv = us2f(u.y); float g = zv/(1.f+__expf(-zv));
        r.y = f2us((us2f(a.y)+us2f(bb.y))*g);
    }{
        float zv = us2f(u.z); float g = zv/(1.f+__expf(-zv));
        r.z = f2us((us2f(a.z)+us2f(bb.z))*g);
    }{
        float zv = us2f(u.w); float g = zv/(1.f+__expf(-zv));
        r.w = f2us((us2f(a.w)+us2f(bb.w))*g);
    }
    *(ushort4*)(out + i4) = r;
}

// ---------------- final rmsnorm (read-only res) ----------------------------------
__global__ __launch_bounds__(128) void rmsnorm_final_kernel(
        const float* __restrict__ res,
        const float* __restrict__ w, float* __restrict__ out)
{
    int r = blockIdx.x; int tid = threadIdx.x;
    const float* rr = res + (long)r*DM;
    float v[3]; float ss = 0.f;
    #pragma unroll
    for (int i = 0; i < 3; i++){
        int c = tid + i*128;
        float x = rr[c];
        v[i] = x; ss += x*x;
    }
    #pragma unroll
    for (int off = 32; off; off >>= 1) ss += __shfl_down(ss, off, 64);
    __shared__ float wsum[2];
    if ((tid & 63) == 0) wsum[tid >> 6] = ss;
    __syncthreads();
    float scale = rsqrtf((wsum[0] + wsum[1]) / (float)DM + EPS_);
    #pragma unroll
    for (int i = 0; i < 3; i++){
        int c = tid + i*128;
        out[(long)r*DM + c] = v[i] * scale * w[c];
    }
}

extern "C" void kernel_launch(void* const* d_in, const int* in_sizes, int n_in,
                              void* d_out, int out_size, void* d_ws, size_t ws_size,
                              hipStream_t stream)
{
    const float* x         = (const float*)d_in[0];
    const float* patch_w   = (const float*)d_in[1];
    const float* patch_b   = (const float*)d_in[2];
    const float* pos_embed = (const float*)d_in[3];
    const float* temp_pos  = (const float*)d_in[4];
    const float* in_proj   = (const float*)d_in[5];
    const float* conv_w    = (const float*)d_in[6];
    const float* conv_b    = (const float*)d_in[7];
    const float* xproj_w   = (const float*)d_in[8];
    const float* dt_w      = (const float*)d_in[9];
    const float* dt_b      = (const float*)d_in[10];
    const float* A_log     = (const float*)d_in[11];
    const float* Dp        = (const float*)d_in[12];
    const float* conv_w_b  = (const float*)d_in[13];
    const float* conv_b_b  = (const float*)d_in[14];
    const float* xproj_w_b = (const float*)d_in[15];
    const float* dt_w_b    = (const float*)d_in[16];
    const float* dt_b_b    = (const float*)d_in[17];
    const float* A_log_b   = (const float*)d_in[18];
    const float* Dp_b      = (const float*)d_in[19];
    const float* out_proj  = (const float*)d_in[20];
    const float* norm_w    = (const float*)d_in[21];
    const float* norm_f    = (const float*)d_in[22];

    float* ws = (float*)d_ws;
    size_t off = 0;
    float* residual = ws + off; off += (size_t)NROWS*DM;           // 1,204,224
    float* hnormreg = ws + off; off += (size_t)NROWS*DM/2;         // bf16 hnorm; Pbuf head
    float* xireg    = ws + off; off += (size_t)NROWS*DI/2;         // bf16 xi; Pbuf tail
    float* zireg    = ws + off; off += (size_t)NROWS*DI/2;         // bf16 zi; ys_bf alias
    float* xc2bfreg = ws + off; off += (size_t)NROWS*DI;           // bf16 xc, 2 dirs
    float* xdbl2    = ws + off; off += (size_t)2*NROWS*56;
    float* xdblbf_f = ws + off; off += (size_t)2*NROWS*32/2;
    float* dt2bfreg = ws + off; off += (size_t)NROWS*DI;           // bf16 dt, 2 dirs; patches alias
    float* ysfbfreg = ws + off; off += (size_t)NROWS*DI/2;
    float* ysbbfreg = ws + off; off += (size_t)NROWS*DI/2;
    float* Sbuf     = ws + off; off += (size_t)4*NCHUNK*DI*DS;     // 1,572,864
    float* wpbf_f   = ws + off; off += (size_t)(DM*DI+1)/2;
    size_t fixed_floats = off;
    const size_t perW = (size_t)(WCVT_TOTAL+1)/2;
    int G = (ws_size/4 >= fixed_floats + 24*perW) ? 24
          : (ws_size/4 >= fixed_floats + 8*perW)  ? 8 : 1;
    float* wbf_f = ws + off; off += G*perW;

    ushort_t* hnorm_bf   = (ushort_t*)hnormreg;
    ushort_t* xi_bf      = (ushort_t*)xireg;
    ushort_t* zi_bf      = (ushort_t*)zireg;
    ushort_t* ys_bf      = (ushort_t*)zireg;   // gate reads zi[i], writes out[i]: safe
    ushort_t* xc2_bf     = (ushort_t*)xc2bfreg;
    ushort_t* xdbl_bf    = (ushort_t*)xdblbf_f;
    ushort_t* dt2_bf     = (ushort_t*)dt2bfreg;
    ushort_t* ysf_bf     = (ushort_t*)ysfbfreg;
    ushort_t* ysb_bf     = (ushort_t*)ysbbfreg;
    ushort_t* patches_bf = (ushort_t*)dt2bfreg;  // dead before dt GEMM of layer 0
    ushort_t* wbuf       = (ushort_t*)wbf_f;
    ushort_t* wp_bf      = (ushort_t*)wpbf_f;
    float* Pbuf = hnormreg;   // spans hnorm+xi; both dead by pass1

    patchify_kernel<<<(NROWS*768+255)/256, 256, 0, stream>>>(x, patches_bf);
    convert_kernel<<<(DM*DI+255)/256, 256, 0, stream>>>(patch_w, wp_bf, DM*DI);
    gemm_mfma_kernel<4,1><<<dim3(DM/64, NROWS/64, 1), 256, 0, stream>>>(
        patches_bf, DI, 0, wp_bf, DI, 0, DI, DM,
        residual, 0, nullptr, nullptr, 0, 2, patch_b, pos_embed, temp_pos);

    for (int l = 0; l < DEPTH; l++){
        if (l % G == 0){
            int cnt = (DEPTH - l < G) ? DEPTH - l : G;
            long total = (long)cnt*WCVT_TOTAL;
            convert_group_kernel<<<(int)((total+255)/256), 256, 0, stream>>>(
                in_proj, out_proj, xproj_w, xproj_w_b, dt_w, dt_w_b,
                wbuf, l, cnt);
        }
        ushort_t* wl = wbuf + (size_t)(l % G)*WCVT_TOTAL;
        ushort_t* wi_bf  = wl;
        ushort_t* wo_bf  = wl + WI_SZ;
        ushort_t* wx_bf  = wl + WI_SZ + WO_SZ;
        ushort_t* wdt_bf = wl + WI_SZ + WO_SZ + 2*WX_SZ;

        rmsnorm_kernel<<<NROWS, 128, 0, stream>>>(residual, hnorm_bf,
                                                  norm_w + (size_t)l*DM);
        gemm_mfma_kernel<4,1><<<dim3(2*DI/64, NROWS/64, 1), 256, 0, stream>>>(
            hnorm_bf, DM, 0, wi_bf, DM, 0, DM, 2*DI,
            nullptr, 0, xi_bf, zi_bf, 0, 1, nullptr, nullptr, nullptr);

        conv_kernel<<<(2*NROWS*192+255)/256, 256, 0, stream>>>(
            xi_bf, conv_w + (size_t)l*DI*KCONV, conv_b + (size_t)l*DI,
            conv_w_b + (size_t)l*DI*KCONV, conv_b_b + (size_t)l*DI, xc2_bf);

        gemm_mfma_kernel<1,1><<<dim3(1, NROWS/16, 2), 256, 0, stream>>>(
            xc2_bf, DI, (long)NROWS*DI, wx_bf, DI, WX_SZ, DI, 64,
            xdbl2, (long)NROWS*56, xdbl_bf, nullptr, (long)NROWS*32, 4,
            nullptr, nullptr, nullptr);

        gemm_mfma_kernel<4,0><<<dim3(DI/64, NROWS/64, 2), 256, 0, stream>>>(
            xdbl_bf, 32, (long)NROWS*32, wdt_bf, 32, WDT_SZ, 32, DI,
            nullptr, 0, dt2_bf, nullptr, (long)NROWS*DI, 3,
            dt_b + (size_t)l*DI, dt_b_b + (size_t)l*DI, nullptr);

        scan_pass1_kernel<<<dim3(NDC, NCHUNK, 4), 256, 0, stream>>>(
            xc2_bf, dt2_bf, xdbl2, A_log + (size_t)l*DI*DS, A_log_b + (size_t)l*DI*DS,
            Pbuf, Sbuf);
        scan_combine_kernel<<<(4*DI*DS/4+255)/256, 256, 0, stream>>>(Pbuf, Sbuf);
        scan_pass2_kernel<<<dim3(NDC, NCHUNK, 4), 256, 0, stream>>>(
            xc2_bf, dt2_bf, xdbl2,
            A_log + (size_t)l*DI*DS, Dp + (size_t)l*DI,
            A_log_b + (size_t)l*DI*DS, Dp_b + (size_t)l*DI,
            Sbuf, ysf_bf, ysb_bf);

        ys_gate_kernel<<<(NROWS*DI/4+255)/256, 256, 0, stream>>>(ysf_bf, ysb_bf, zi_bf, ys_bf);

        gemm_mfma_kernel<4,1><<<dim3(DM/64, NROWS/64, 1), 256, 0, stream>>>(
            ys_bf, DI, 0, wo_bf, DI, 0, DI, DM,
            residual, 0, nullptr, nullptr, 0, 0, nullptr, nullptr, nullptr);
    }

    rmsnorm_final_kernel<<<NROWS, 128, 0, stream>>>(residual, norm_f, (float*)d_out);
}